// Round 1
// baseline (2458.084 us; speedup 1.0000x reference)
//
#include <hip/hip_runtime.h>
#include <cmath>

// Problem constants
#define TT 2048
#define CC 1024
#define HH 16
#define SKEEP 512
// head dim = 96 (32 nope + 64 rope), value head dim = 96, H*96 = 1536

// ---------------- workspace layout (float offsets) ----------------
static constexpr size_t OFF_COS   = 0;                        // 2048*32
static constexpr size_t OFF_SIN   = OFF_COS   + 65536;        // 2048*32
static constexpr size_t OFF_QLAT  = OFF_SIN   + 65536;        // 2048*96
static constexpr size_t OFF_KVLAT = OFF_QLAT  + 196608;       // 2048*32
static constexpr size_t OFF_GACC  = OFF_KVLAT + 65536;        // 64
static constexpr size_t OFF_GATE  = OFF_GACC  + 64;           // 64
static constexpr size_t OFF_SCORE = OFF_GATE  + 64;           // 2048
static constexpr size_t OFF_IDX   = OFF_SCORE + 2048;         // 512 (ints)
static constexpr size_t OFF_SELX  = OFF_IDX   + 512;          // 512*1024
static constexpr size_t OFF_FLAT  = OFF_SELX  + 524288;       // 2048*1536 scratch; ALSO o_comb (reuse is safe: flat last read before attention starts)
static constexpr size_t OFF_QF    = OFF_FLAT  + 3145728;      // 2048*1536
static constexpr size_t OFF_K1    = OFF_QF    + 3145728;
static constexpr size_t OFF_V1    = OFF_K1    + 3145728;
static constexpr size_t OFF_KW    = OFF_V1    + 3145728;
static constexpr size_t OFF_VW    = OFF_KW    + 3145728;
static constexpr size_t OFF_KS    = OFF_VW    + 3145728;      // 512*1536
static constexpr size_t OFF_VS    = OFF_KS    + 786432;       // 512*1536
static constexpr size_t WS_FLOATS = OFF_VS    + 786432;       // ~85.5 MB

// ---------------- RoPE tables (match numpy f32 pipeline) ----------------
__global__ void rope_table_kernel(float* __restrict__ cosT, float* __restrict__ sinT) {
    int i = blockIdx.x * blockDim.x + threadIdx.x;
    if (i >= TT * 32) return;
    int t = i >> 5, j = i & 31;
    // inv = 10000^(-j/32) computed in double then rounded to f32 (matches numpy f32 value to ~1 ulp)
    float inv = (float)exp(-(double)j * (9.210340371976184 / 32.0));
    float f = (float)t * inv;               // f32 rounding as in np.outer(float32)
    cosT[i] = (float)cos((double)f);
    sinT[i] = (float)sin((double)f);
}

// ---------------- generic f32 GEMM: C[M,N] = A[M,K] * B[K,N] ----------------
// requires: M % 64 == 0, K % 16 == 0. N arbitrary (guarded).
__global__ __launch_bounds__(256) void gemm_f32(const float* __restrict__ A,
                                                const float* __restrict__ B,
                                                float* __restrict__ C,
                                                int M, int N, int K) {
    __shared__ float As[16][68];
    __shared__ float Bs[16][68];
    const int tid = threadIdx.x;
    const int m0 = blockIdx.y * 64;
    const int n0 = blockIdx.x * 64;
    const int tx = tid & 15;          // col group
    const int ty = tid >> 4;          // row group
    const int ar = tid >> 2;          // A tile row 0..63
    const int ak = (tid & 3) << 2;    // A tile k 0,4,8,12
    const int br = tid >> 4;          // B tile row 0..15
    const int bc = (tid & 15) << 2;   // B tile col 0..60
    const bool bvec = (n0 + bc + 3) < N;
    float acc[4][4] = {};
    for (int k0 = 0; k0 < K; k0 += 16) {
        float4 av = *(const float4*)(A + (size_t)(m0 + ar) * K + k0 + ak);
        As[ak + 0][ar] = av.x; As[ak + 1][ar] = av.y;
        As[ak + 2][ar] = av.z; As[ak + 3][ar] = av.w;
        if (bvec) {
            *(float4*)&Bs[br][bc] = *(const float4*)(B + (size_t)(k0 + br) * N + n0 + bc);
        } else {
            #pragma unroll
            for (int j = 0; j < 4; ++j) {
                int col = n0 + bc + j;
                Bs[br][bc + j] = (col < N) ? B[(size_t)(k0 + br) * N + col] : 0.f;
            }
        }
        __syncthreads();
        #pragma unroll
        for (int kk = 0; kk < 16; ++kk) {
            float a[4], b[4];
            #pragma unroll
            for (int i = 0; i < 4; ++i) a[i] = As[kk][ty * 4 + i];
            #pragma unroll
            for (int j = 0; j < 4; ++j) b[j] = Bs[kk][tx * 4 + j];
            #pragma unroll
            for (int i = 0; i < 4; ++i)
                #pragma unroll
                for (int j = 0; j < 4; ++j)
                    acc[i][j] += a[i] * b[j];
        }
        __syncthreads();
    }
    #pragma unroll
    for (int i = 0; i < 4; ++i) {
        int row = m0 + ty * 4 + i;
        if (row >= M) continue;
        #pragma unroll
        for (int j = 0; j < 4; ++j) {
            int col = n0 + tx * 4 + j;
            if (col < N) C[(size_t)row * N + col] = acc[i][j];
        }
    }
}

// ---------------- RMSNorm rows in place ----------------
__global__ __launch_bounds__(64) void rms_kernel(float* __restrict__ buf,
                                                 const float* __restrict__ scale,
                                                 int D) {
    int t = blockIdx.x;
    int lane = threadIdx.x;
    float* row = buf + (size_t)t * D;
    float ss = 0.f;
    for (int d = lane; d < D; d += 64) { float v = row[d]; ss += v * v; }
    #pragma unroll
    for (int o = 32; o > 0; o >>= 1) ss += __shfl_xor(ss, o);
    float rs = 1.0f / sqrtf(ss / (float)D + 1e-6f);
    for (int d = lane; d < D; d += 64) row[d] = row[d] * rs * scale[d];
}

// ---------------- gate partial sums + importance scores ----------------
__global__ void zero_gacc_kernel(float* __restrict__ g) {
    if (threadIdx.x < 64 && blockIdx.x == 0) g[threadIdx.x] = 0.f;
}

__global__ __launch_bounds__(256) void gate_scores_kernel(const float* __restrict__ x,
                                                          const float* __restrict__ w_gate,
                                                          const float* __restrict__ w_imp,
                                                          const float* __restrict__ b_imp,
                                                          float* __restrict__ gate_acc,
                                                          float* __restrict__ scores) {
    int t = blockIdx.x;
    const float* xr = x + (size_t)t * CC;
    float g0 = 0, g1 = 0, g2 = 0, si = 0;
    for (int c = threadIdx.x; c < CC; c += 256) {
        float xv = xr[c];
        g0 += xv * w_gate[c * 3 + 0];
        g1 += xv * w_gate[c * 3 + 1];
        g2 += xv * w_gate[c * 3 + 2];
        si += xv * w_imp[c];
    }
    #pragma unroll
    for (int o = 32; o > 0; o >>= 1) {
        g0 += __shfl_xor(g0, o); g1 += __shfl_xor(g1, o);
        g2 += __shfl_xor(g2, o); si += __shfl_xor(si, o);
    }
    __shared__ float red[4][4];
    int w_ = threadIdx.x >> 6, lane = threadIdx.x & 63;
    if (lane == 0) { red[w_][0] = g0; red[w_][1] = g1; red[w_][2] = g2; red[w_][3] = si; }
    __syncthreads();
    if (threadIdx.x == 0) {
        float a0 = red[0][0] + red[1][0] + red[2][0] + red[3][0];
        float a1 = red[0][1] + red[1][1] + red[2][1] + red[3][1];
        float a2 = red[0][2] + red[1][2] + red[2][2] + red[3][2];
        float aS = red[0][3] + red[1][3] + red[2][3] + red[3][3];
        atomicAdd(&gate_acc[0], a0);
        atomicAdd(&gate_acc[1], a1);
        atomicAdd(&gate_acc[2], a2);
        scores[t] = aS + b_imp[0];
    }
}

__global__ void gate_finalize_kernel(const float* __restrict__ gacc,
                                     const float* __restrict__ b_gate,
                                     float* __restrict__ gate) {
    if (threadIdx.x == 0 && blockIdx.x == 0) {
        float g0 = gacc[0] / (float)TT + b_gate[0];
        float g1 = gacc[1] / (float)TT + b_gate[1];
        float g2 = gacc[2] / (float)TT + b_gate[2];
        float mx = fmaxf(g0, fmaxf(g1, g2));
        float e0 = __expf(g0 - mx), e1 = __expf(g1 - mx), e2 = __expf(g2 - mx);
        float s = e0 + e1 + e2;
        gate[0] = e0 / s; gate[1] = e1 / s; gate[2] = e2 / s;
    }
}

// ---------------- top-k (single block bitonic; matches lax.top_k tie semantics) ----------------
__global__ __launch_bounds__(1024) void topk_kernel(const float* __restrict__ scores,
                                                    int* __restrict__ idx_out) {
    __shared__ float v[2048];
    __shared__ int ixs[2048];
    int tid = threadIdx.x;
    v[tid] = scores[tid];          ixs[tid] = tid;
    v[tid + 1024] = scores[tid + 1024]; ixs[tid + 1024] = tid + 1024;
    __syncthreads();
    // full sort: best-first (value desc, index asc on ties)
    for (int k = 2; k <= 2048; k <<= 1) {
        for (int j = k >> 1; j > 0; j >>= 1) {
            #pragma unroll
            for (int half = 0; half < 2; ++half) {
                int i = tid + half * 1024;
                int p = i ^ j;
                if (p > i) {
                    float vi = v[i], vp = v[p];
                    int ii = ixs[i], ip = ixs[p];
                    bool p_before = (vp > vi) || (vp == vi && ip < ii);
                    bool asc = ((i & k) == 0);
                    if (asc ? p_before : !p_before) {
                        v[i] = vp; v[p] = vi; ixs[i] = ip; ixs[p] = ii;
                    }
                }
            }
            __syncthreads();
        }
    }
    // sort the winning 512 indices ascending
    for (int k = 2; k <= 512; k <<= 1) {
        for (int j = k >> 1; j > 0; j >>= 1) {
            if (tid < 512) {
                int i = tid, p = i ^ j;
                if (p > i) {
                    int a = ixs[i], b = ixs[p];
                    bool asc = ((i & k) == 0);
                    bool sw = asc ? (b < a) : (b > a);
                    if (sw) { ixs[i] = b; ixs[p] = a; }
                }
            }
            __syncthreads();
        }
    }
    if (tid < 512) idx_out[tid] = ixs[tid];
}

// ---------------- gather selected rows ----------------
__global__ __launch_bounds__(256) void gather_kernel(const float* __restrict__ x,
                                                     const int* __restrict__ idx,
                                                     float* __restrict__ sel) {
    int i = blockIdx.x * blockDim.x + threadIdx.x;   // SKEEP * 256 float4s
    if (i >= SKEEP * 256) return;
    int s = i >> 8, q = i & 255;
    ((float4*)sel)[(size_t)s * 256 + q] = ((const float4*)x)[(size_t)idx[s] * 256 + q];
}

// ---------------- assemble q/k1 from (nope, rope) latents + RoPE ----------------
__global__ __launch_bounds__(256) void assemble_split_kernel(const float* __restrict__ nope, // [T, H*32]
                                                             const float* __restrict__ rope, // [T, H*64]
                                                             const float* __restrict__ cosT,
                                                             const float* __restrict__ sinT,
                                                             float* __restrict__ out /*[T, H*96]*/) {
    int i = blockIdx.x * blockDim.x + threadIdx.x;  // T*H*32
    if (i >= TT * HH * 32) return;
    int j = i & 31, h = (i >> 5) & 15, t = i >> 9;
    float c = cosT[t * 32 + j], s = sinT[t * 32 + j];
    size_t ob = (size_t)t * 1536 + h * 96;
    out[ob + j] = nope[(size_t)t * 512 + h * 32 + j];
    float a = rope[(size_t)t * 1024 + h * 64 + j];
    float b = rope[(size_t)t * 1024 + h * 64 + 32 + j];
    out[ob + 32 + j] = a * c - b * s;
    out[ob + 64 + j] = a * s + b * c;
}

// ---------------- in-place RoPE on [S, H*96] (last 64 dims of each head), pos = row ----------------
__global__ __launch_bounds__(256) void rope_inplace_kernel(float* __restrict__ buf,
                                                           const float* __restrict__ cosT,
                                                           const float* __restrict__ sinT,
                                                           int S) {
    int i = blockIdx.x * blockDim.x + threadIdx.x;  // S*H*32
    if (i >= S * HH * 32) return;
    int j = i & 31, h = (i >> 5) & 15, t = i >> 9;
    float c = cosT[t * 32 + j], s = sinT[t * 32 + j];
    float* p = buf + (size_t)t * 1536 + h * 96;
    float a = p[32 + j], b = p[64 + j];
    p[32 + j] = a * c - b * s;
    p[64 + j] = a * s + b * c;
}

// ---------------- flash attention over flat [T, H*96] K/V, gated accumulate ----------------
#define QB 32
#define KB 32
template<bool CAUSAL, bool ACCUM>
__global__ __launch_bounds__(256) void flash_attn_kernel(const float* __restrict__ qf,
                                                         const float* __restrict__ kf,
                                                         const float* __restrict__ vf,
                                                         const float* __restrict__ gate,
                                                         int gate_idx,
                                                         float* __restrict__ o_comb,
                                                         int Tkv) {
    __shared__ float qs[QB][100];
    __shared__ float ks[KB][100];
    __shared__ float vs[KB][100];
    __shared__ float sc[QB][KB];
    const int h = blockIdx.y;
    const int t0 = blockIdx.x * QB;
    const int tid = threadIdx.x;
    const int qi = tid >> 3;     // query row in tile
    const int c = tid & 7;       // 8 lanes per query
    const float SCALE = 0.10206207261596575f;  // 1/sqrt(96)

    for (int f = tid; f < QB * 24; f += 256) {
        int r = f / 24, cc = (f % 24) * 4;
        *(float4*)&qs[r][cc] = *(const float4*)&qf[(size_t)(t0 + r) * 1536 + h * 96 + cc];
    }
    float acc[12];
    #pragma unroll
    for (int i = 0; i < 12; ++i) acc[i] = 0.f;
    float m = -1e30f, l = 0.f;
    const int nk = CAUSAL ? (t0 + QB) : Tkv;
    __syncthreads();

    for (int k0 = 0; k0 < nk; k0 += KB) {
        for (int f = tid; f < KB * 24; f += 256) {
            int r = f / 24, cc = (f % 24) * 4;
            *(float4*)&ks[r][cc] = *(const float4*)&kf[(size_t)(k0 + r) * 1536 + h * 96 + cc];
            *(float4*)&vs[r][cc] = *(const float4*)&vf[(size_t)(k0 + r) * 1536 + h * 96 + cc];
        }
        __syncthreads();
        // scores: 4 keys per thread
        float s4[4] = {0.f, 0.f, 0.f, 0.f};
        #pragma unroll 4
        for (int d0 = 0; d0 < 96; d0 += 8) {
            float4 qa = *(const float4*)&qs[qi][d0];
            float4 qb = *(const float4*)&qs[qi][d0 + 4];
            #pragma unroll
            for (int j = 0; j < 4; ++j) {
                const float* krow = &ks[c * 4 + j][0];
                float4 ka = *(const float4*)&krow[d0];
                float4 kb = *(const float4*)&krow[d0 + 4];
                s4[j] += qa.x * ka.x + qa.y * ka.y + qa.z * ka.z + qa.w * ka.w
                       + qb.x * kb.x + qb.y * kb.y + qb.z * kb.z + qb.w * kb.w;
            }
        }
        #pragma unroll
        for (int j = 0; j < 4; ++j) {
            float sv = s4[j] * SCALE;
            if (CAUSAL && (k0 + c * 4 + j) > (t0 + qi)) sv = -1e30f;
            sc[qi][c * 4 + j] = sv;
        }
        __syncthreads();
        // online softmax update (8 lanes of a query are in the same wave)
        float mt = -1e30f;
        #pragma unroll
        for (int kk = 0; kk < KB; ++kk) mt = fmaxf(mt, sc[qi][kk]);
        float mn = fmaxf(m, mt);
        float alpha = __expf(m - mn);
        #pragma unroll
        for (int j = 0; j < 4; ++j) {
            int kg = k0 + c * 4 + j;
            float pj = (CAUSAL && kg > (t0 + qi)) ? 0.f : __expf(sc[qi][c * 4 + j] - mn);
            sc[qi][c * 4 + j] = pj;    // same-wave visibility
        }
        float psum = 0.f;
        #pragma unroll
        for (int kk = 0; kk < KB; ++kk) psum += sc[qi][kk];
        l = l * alpha + psum;
        m = mn;
        #pragma unroll
        for (int i = 0; i < 12; ++i) acc[i] *= alpha;
        // PV: each thread owns 12 dims
        #pragma unroll 8
        for (int kk = 0; kk < KB; ++kk) {
            float p = sc[qi][kk];
            const float4 va = *(const float4*)&vs[kk][c * 12];
            const float4 vb = *(const float4*)&vs[kk][c * 12 + 4];
            const float4 vc4 = *(const float4*)&vs[kk][c * 12 + 8];
            acc[0] += p * va.x;  acc[1] += p * va.y;  acc[2]  += p * va.z;  acc[3]  += p * va.w;
            acc[4] += p * vb.x;  acc[5] += p * vb.y;  acc[6]  += p * vb.z;  acc[7]  += p * vb.w;
            acc[8] += p * vc4.x; acc[9] += p * vc4.y; acc[10] += p * vc4.z; acc[11] += p * vc4.w;
        }
        __syncthreads();
    }
    float inv_l = 1.0f / l;
    float g = gate[gate_idx];
    size_t base = (size_t)(t0 + qi) * 1536 + h * 96 + c * 12;
    #pragma unroll
    for (int i = 0; i < 12; ++i) {
        float val = acc[i] * inv_l * g;
        if (ACCUM) o_comb[base + i] += val;
        else       o_comb[base + i] = val;
    }
}

// ---------------- launch ----------------
extern "C" void kernel_launch(void* const* d_in, const int* in_sizes, int n_in,
                              void* d_out, int out_size, void* d_ws, size_t ws_size,
                              hipStream_t stream) {
    const float* x        = (const float*)d_in[0];
    const float* w_cq     = (const float*)d_in[1];
    const float* q_scale  = (const float*)d_in[2];
    const float* w_dq_n   = (const float*)d_in[3];
    const float* w_dq_r   = (const float*)d_in[4];
    const float* w_ckv    = (const float*)d_in[5];
    const float* kv_scale = (const float*)d_in[6];
    const float* w_dk_n   = (const float*)d_in[7];
    const float* w_dv     = (const float*)d_in[8];
    const float* w_k_r    = (const float*)d_in[9];
    const float* w_imp    = (const float*)d_in[10];
    const float* b_imp    = (const float*)d_in[11];
    const float* w_sel_k  = (const float*)d_in[12];
    const float* w_sel_v  = (const float*)d_in[13];
    const float* w_win_k  = (const float*)d_in[14];
    const float* w_win_v  = (const float*)d_in[15];
    const float* w_gate   = (const float*)d_in[16];
    const float* b_gate   = (const float*)d_in[17];
    const float* w_proj   = (const float*)d_in[18];
    float* out = (float*)d_out;
    float* w = (float*)d_ws;

    float* cosT  = w + OFF_COS;
    float* sinT  = w + OFF_SIN;
    float* q_lat = w + OFF_QLAT;
    float* kvlat = w + OFF_KVLAT;
    float* gacc  = w + OFF_GACC;
    float* gate  = w + OFF_GATE;
    float* score = w + OFF_SCORE;
    int*   idx   = (int*)(w + OFF_IDX);
    float* selx  = w + OFF_SELX;
    float* flat  = w + OFF_FLAT;      // scratch for (qn|qr) then (kn|kr); later o_comb
    float* ocomb = w + OFF_FLAT;
    float* qfl   = w + OFF_QF;
    float* k1f   = w + OFF_K1;
    float* v1f   = w + OFF_V1;
    float* kwf   = w + OFF_KW;
    float* vwf   = w + OFF_VW;
    float* ksf   = w + OFF_KS;
    float* vsf   = w + OFF_VS;

    // 0) tables + zero accumulators
    rope_table_kernel<<<dim3((TT * 32 + 255) / 256), dim3(256), 0, stream>>>(cosT, sinT);
    zero_gacc_kernel<<<dim3(1), dim3(64), 0, stream>>>(gacc);

    // 1) latents: q_lat = rms(x@w_cq)*q_scale ; kvlat = rms(x@w_ckv)*kv_scale
    gemm_f32<<<dim3(2, 32), dim3(256), 0, stream>>>(x, w_cq, q_lat, TT, 96, CC);
    gemm_f32<<<dim3(1, 32), dim3(256), 0, stream>>>(x, w_ckv, kvlat, TT, 32, CC);
    rms_kernel<<<dim3(TT), dim3(64), 0, stream>>>(q_lat, q_scale, 96);
    rms_kernel<<<dim3(TT), dim3(64), 0, stream>>>(kvlat, kv_scale, 32);

    // 2) gate + importance scores; top-k; gather
    gate_scores_kernel<<<dim3(TT), dim3(256), 0, stream>>>(x, w_gate, w_imp, b_imp, gacc, score);
    gate_finalize_kernel<<<dim3(1), dim3(64), 0, stream>>>(gacc, b_gate, gate);
    topk_kernel<<<dim3(1), dim3(1024), 0, stream>>>(score, idx);
    gather_kernel<<<dim3((SKEEP * 256 + 255) / 256), dim3(256), 0, stream>>>(x, idx, selx);

    // 3) Q: q_lat @ w_dq_nope | w_dq_rope -> rope-assemble [T, H*96]
    gemm_f32<<<dim3(8, 32), dim3(256), 0, stream>>>(q_lat, w_dq_n, flat, TT, 512, 96);
    gemm_f32<<<dim3(16, 32), dim3(256), 0, stream>>>(q_lat, w_dq_r, flat + (size_t)TT * 512, TT, 1024, 96);
    assemble_split_kernel<<<dim3((TT * HH * 32 + 255) / 256), dim3(256), 0, stream>>>(
        flat, flat + (size_t)TT * 512, cosT, sinT, qfl);

    // 4) K1: kvlat @ w_dk_nope | w_k_rope -> rope-assemble ; V1 = kvlat @ w_dv
    gemm_f32<<<dim3(8, 32), dim3(256), 0, stream>>>(kvlat, w_dk_n, flat, TT, 512, 32);
    gemm_f32<<<dim3(16, 32), dim3(256), 0, stream>>>(kvlat, w_k_r, flat + (size_t)TT * 512, TT, 1024, 32);
    assemble_split_kernel<<<dim3((TT * HH * 32 + 255) / 256), dim3(256), 0, stream>>>(
        flat, flat + (size_t)TT * 512, cosT, sinT, k1f);
    gemm_f32<<<dim3(24, 32), dim3(256), 0, stream>>>(kvlat, w_dv, v1f, TT, 1536, 32);

    // 5) window branch K/V
    gemm_f32<<<dim3(24, 32), dim3(256), 0, stream>>>(x, w_win_k, kwf, TT, 1536, CC);
    rope_inplace_kernel<<<dim3((TT * HH * 32 + 255) / 256), dim3(256), 0, stream>>>(kwf, cosT, sinT, TT);
    gemm_f32<<<dim3(24, 32), dim3(256), 0, stream>>>(x, w_win_v, vwf, TT, 1536, CC);

    // 6) selected branch K/V (rope positions = selected-row index 0..511)
    gemm_f32<<<dim3(24, 8), dim3(256), 0, stream>>>(selx, w_sel_k, ksf, SKEEP, 1536, CC);
    rope_inplace_kernel<<<dim3((SKEEP * HH * 32 + 255) / 256), dim3(256), 0, stream>>>(ksf, cosT, sinT, SKEEP);
    gemm_f32<<<dim3(24, 8), dim3(256), 0, stream>>>(selx, w_sel_v, vsf, SKEEP, 1536, CC);

    // 7) three attentions, gated accumulate into o_comb [T, H*96]
    flash_attn_kernel<true, false><<<dim3(TT / QB, HH), dim3(256), 0, stream>>>(
        qfl, k1f, v1f, gate, 0, ocomb, TT);
    flash_attn_kernel<false, true><<<dim3(TT / QB, HH), dim3(256), 0, stream>>>(
        qfl, ksf, vsf, gate, 1, ocomb, SKEEP);
    flash_attn_kernel<true, true><<<dim3(TT / QB, HH), dim3(256), 0, stream>>>(
        qfl, kwf, vwf, gate, 2, ocomb, TT);

    // 8) output projection
    gemm_f32<<<dim3(16, 32), dim3(256), 0, stream>>>(ocomb, w_proj, out, TT, CC, 1536);
}

// Round 2
// 865.835 us; speedup vs baseline: 2.8390x; 2.8390x over previous
//
#include <hip/hip_runtime.h>
#include <cmath>

#define TT 2048
#define CC 1024
#define HH 16
#define SKEEP 512

typedef __attribute__((ext_vector_type(8))) short bf16x8;
typedef __attribute__((ext_vector_type(4))) float f32x4;
typedef __attribute__((ext_vector_type(8))) unsigned short u16x8;

__device__ __forceinline__ unsigned short f2bf(float f) {
    union { float f; unsigned int u; } v; v.f = f;
    unsigned int r = v.u + 0x7fffu + ((v.u >> 16) & 1u);
    return (unsigned short)(r >> 16);
}
__device__ __forceinline__ float bf2f(unsigned short b) {
    union { unsigned int u; float f; } v; v.u = ((unsigned int)b) << 16;
    return v.f;
}

#define GLOAD16(gp, lp) __builtin_amdgcn_global_load_lds( \
    (const __attribute__((address_space(1))) void*)(gp),  \
    (__attribute__((address_space(3))) void*)(lp), 16, 0, 0)

// ---------------- workspace byte offsets ----------------
static constexpr size_t B_COS   = 0;                        // 2048*32 f32
static constexpr size_t B_SIN   = B_COS   + 262144;
static constexpr size_t B_XB    = B_SIN   + 262144;         // 2048*1024 bf16
static constexpr size_t B_WCQT  = B_XB    + 4194304;        // 128x1024 bf16 (pad 96->128)
static constexpr size_t B_WDQN  = B_WCQT  + 262144;         // 512x96
static constexpr size_t B_WDQR  = B_WDQN  + 98304;          // 1024x96
static constexpr size_t B_WCKVT = B_WDQR  + 196608;         // 128x1024 (pad 32->128)
static constexpr size_t B_WDKN  = B_WCKVT + 262144;         // 512x32
static constexpr size_t B_WDVT  = B_WDKN  + 32768;          // 1536x32
static constexpr size_t B_WKRT  = B_WDVT  + 98304;          // 1024x32
static constexpr size_t B_WSELK = B_WKRT  + 65536;          // 1536x1024
static constexpr size_t B_WSELV = B_WSELK + 3145728;
static constexpr size_t B_WWINK = B_WSELV + 3145728;
static constexpr size_t B_WWINV = B_WWINK + 3145728;
static constexpr size_t B_WPROJ = B_WWINV + 3145728;        // 1024x1536
static constexpr size_t B_QLATF = B_WPROJ + 3145728;        // 2048*96 f32
static constexpr size_t B_KVLATF= B_QLATF + 786432;         // 2048*32 f32
static constexpr size_t B_QLATB = B_KVLATF+ 262144;         // 2048*96 bf16
static constexpr size_t B_KVLATB= B_QLATB + 393216;         // 2048*32 bf16
static constexpr size_t B_GACC  = B_KVLATB+ 131072;
static constexpr size_t B_GATE  = B_GACC  + 256;
static constexpr size_t B_SCORE = B_GATE  + 256;            // 2048 f32
static constexpr size_t B_IDX   = B_SCORE + 8192;           // 512 int
static constexpr size_t B_SELXB = B_IDX   + 2048;           // 512*1024 bf16
static constexpr size_t B_FLATN = B_SELXB + 1048576;        // 2048*512 bf16
static constexpr size_t B_FLATR = B_FLATN + 2097152;        // 2048*1024 bf16
static constexpr size_t B_QFB   = B_FLATR + 4194304;        // 2048*1536 bf16
static constexpr size_t B_K1B   = B_QFB   + 6291456;
static constexpr size_t B_V1B   = B_K1B   + 6291456;
static constexpr size_t B_KWB   = B_V1B   + 6291456;
static constexpr size_t B_VWB   = B_KWB   + 6291456;
static constexpr size_t B_KSB   = B_VWB   + 6291456;        // 512*1536 bf16
static constexpr size_t B_VSB   = B_KSB   + 1572864;
static constexpr size_t B_OB    = B_VSB   + 1572864;        // 2048*1536 bf16

// ---------------- RoPE tables ----------------
__global__ void rope_table_kernel(float* __restrict__ cosT, float* __restrict__ sinT) {
    int i = blockIdx.x * blockDim.x + threadIdx.x;
    if (i >= TT * 32) return;
    int t = i >> 5, j = i & 31;
    float inv = (float)exp(-(double)j * (9.210340371976184 / 32.0));
    float f = (float)t * inv;
    cosT[i] = (float)cos((double)f);
    sinT[i] = (float)sin((double)f);
}

// ---------------- f32 -> bf16 convert (4-wide) ----------------
__global__ __launch_bounds__(256) void convert_kernel(const float* __restrict__ src,
                                                      unsigned short* __restrict__ dst, int n4) {
    int i = blockIdx.x * 256 + threadIdx.x;
    if (i >= n4) return;
    float4 v = ((const float4*)src)[i];
    ushort4 o;
    o.x = f2bf(v.x); o.y = f2bf(v.y); o.z = f2bf(v.z); o.w = f2bf(v.w);
    ((ushort4*)dst)[i] = o;
}

// ---------------- transpose-convert: src f32 [K,N] -> dst bf16 [NP,K] (pad rows zero) ----------------
__global__ __launch_bounds__(256) void tconv_kernel(const float* __restrict__ src,
                                                    unsigned short* __restrict__ dst,
                                                    int K, int N) {
    __shared__ float tile[32][33];
    int n0 = blockIdx.x * 32, k0 = blockIdx.y * 32;
    int tx = threadIdx.x & 31, ty = threadIdx.x >> 5;
    #pragma unroll
    for (int r = ty; r < 32; r += 8) {
        float v = 0.f;
        if (n0 + tx < N) v = src[(size_t)(k0 + r) * N + n0 + tx];
        tile[r][tx] = v;
    }
    __syncthreads();
    #pragma unroll
    for (int r = ty; r < 32; r += 8)
        dst[(size_t)(n0 + r) * K + k0 + tx] = f2bf(tile[tx][r]);
}

// ---------------- bf16 MFMA GEMM: C[M,N] = A[M,K] * BT[N,K]^T ----------------
// M%128==0, K%32==0; BT must have ceil(N/128)*128 rows (pad zeros). grid (ceil(N/128), M/128)
template<typename OUTT>
__global__ __launch_bounds__(256) void gemm_bf16(const unsigned short* __restrict__ A,
                                                 const unsigned short* __restrict__ BT,
                                                 OUTT* __restrict__ C,
                                                 int M, int N, int K) {
    __shared__ unsigned short As[128 * 32];
    __shared__ unsigned short Bs[128 * 32];
    const int tid = threadIdx.x;
    const int m0 = blockIdx.y * 128, n0 = blockIdx.x * 128;
    const int lane = tid & 63, lr = lane & 15, lg = lane >> 4;
    const int wave = tid >> 6;
    const int wm = (wave & 1) * 64, wn = (wave >> 1) * 64;
    f32x4 acc[4][4];
    #pragma unroll
    for (int i = 0; i < 4; ++i)
        #pragma unroll
        for (int j = 0; j < 4; ++j) acc[i][j] = (f32x4){0.f, 0.f, 0.f, 0.f};
    const int ar = tid >> 2, ak = (tid & 3) * 8;
    const unsigned short* ga = A + (size_t)(m0 + ar) * K + ak;
    const unsigned short* gb = BT + (size_t)(n0 + ar) * K + ak;
    for (int k0 = 0; k0 < K; k0 += 32) {
        GLOAD16(ga + k0, &As[tid * 8]);
        GLOAD16(ga + (size_t)64 * K + k0, &As[2048 + tid * 8]);
        GLOAD16(gb + k0, &Bs[tid * 8]);
        GLOAD16(gb + (size_t)64 * K + k0, &Bs[2048 + tid * 8]);
        __syncthreads();
        bf16x8 af[4], bfr[4];
        #pragma unroll
        for (int i = 0; i < 4; ++i) af[i] = *(const bf16x8*)&As[(wm + i * 16 + lr) * 32 + lg * 8];
        #pragma unroll
        for (int j = 0; j < 4; ++j) bfr[j] = *(const bf16x8*)&Bs[(wn + j * 16 + lr) * 32 + lg * 8];
        #pragma unroll
        for (int i = 0; i < 4; ++i)
            #pragma unroll
            for (int j = 0; j < 4; ++j)
                acc[i][j] = __builtin_amdgcn_mfma_f32_16x16x32_bf16(af[i], bfr[j], acc[i][j], 0, 0, 0);
        __syncthreads();
    }
    #pragma unroll
    for (int i = 0; i < 4; ++i) {
        #pragma unroll
        for (int r = 0; r < 4; ++r) {
            int row = m0 + wm + i * 16 + lg * 4 + r;
            #pragma unroll
            for (int j = 0; j < 4; ++j) {
                int col = n0 + wn + j * 16 + lr;
                if (col < N) {
                    float v = acc[i][j][r];
                    if constexpr (__is_same(OUTT, float)) C[(size_t)row * N + col] = v;
                    else                                  C[(size_t)row * N + col] = f2bf(v);
                }
            }
        }
    }
}

// ---------------- RMSNorm: f32 in -> bf16 out ----------------
__global__ __launch_bounds__(64) void rms_kernel(const float* __restrict__ in,
                                                 unsigned short* __restrict__ outb,
                                                 const float* __restrict__ scale, int D) {
    int t = blockIdx.x, lane = threadIdx.x;
    const float* row = in + (size_t)t * D;
    float ss = 0.f;
    for (int d = lane; d < D; d += 64) { float v = row[d]; ss += v * v; }
    #pragma unroll
    for (int o = 32; o > 0; o >>= 1) ss += __shfl_xor(ss, o);
    float rs = 1.0f / sqrtf(ss / (float)D + 1e-6f);
    for (int d = lane; d < D; d += 64) outb[(size_t)t * D + d] = f2bf(row[d] * rs * scale[d]);
}

// ---------------- gate + importance scores (f32 exactness for top-k) ----------------
__global__ void zero_gacc_kernel(float* __restrict__ g) {
    if (threadIdx.x < 64 && blockIdx.x == 0) g[threadIdx.x] = 0.f;
}

__global__ __launch_bounds__(256) void gate_scores_kernel(const float* __restrict__ x,
                                                          const float* __restrict__ w_gate,
                                                          const float* __restrict__ w_imp,
                                                          const float* __restrict__ b_imp,
                                                          float* __restrict__ gate_acc,
                                                          float* __restrict__ scores) {
    int t = blockIdx.x;
    const float* xr = x + (size_t)t * CC;
    float g0 = 0, g1 = 0, g2 = 0, si = 0;
    for (int c = threadIdx.x; c < CC; c += 256) {
        float xv = xr[c];
        g0 += xv * w_gate[c * 3 + 0];
        g1 += xv * w_gate[c * 3 + 1];
        g2 += xv * w_gate[c * 3 + 2];
        si += xv * w_imp[c];
    }
    #pragma unroll
    for (int o = 32; o > 0; o >>= 1) {
        g0 += __shfl_xor(g0, o); g1 += __shfl_xor(g1, o);
        g2 += __shfl_xor(g2, o); si += __shfl_xor(si, o);
    }
    __shared__ float red[4][4];
    int w_ = threadIdx.x >> 6, lane = threadIdx.x & 63;
    if (lane == 0) { red[w_][0] = g0; red[w_][1] = g1; red[w_][2] = g2; red[w_][3] = si; }
    __syncthreads();
    if (threadIdx.x == 0) {
        atomicAdd(&gate_acc[0], red[0][0] + red[1][0] + red[2][0] + red[3][0]);
        atomicAdd(&gate_acc[1], red[0][1] + red[1][1] + red[2][1] + red[3][1]);
        atomicAdd(&gate_acc[2], red[0][2] + red[1][2] + red[2][2] + red[3][2]);
        scores[t] = red[0][3] + red[1][3] + red[2][3] + red[3][3] + b_imp[0];
    }
}

__global__ void gate_finalize_kernel(const float* __restrict__ gacc,
                                     const float* __restrict__ b_gate,
                                     float* __restrict__ gate) {
    if (threadIdx.x == 0 && blockIdx.x == 0) {
        float g0 = gacc[0] / (float)TT + b_gate[0];
        float g1 = gacc[1] / (float)TT + b_gate[1];
        float g2 = gacc[2] / (float)TT + b_gate[2];
        float mx = fmaxf(g0, fmaxf(g1, g2));
        float e0 = __expf(g0 - mx), e1 = __expf(g1 - mx), e2 = __expf(g2 - mx);
        float s = e0 + e1 + e2;
        gate[0] = e0 / s; gate[1] = e1 / s; gate[2] = e2 / s;
    }
}

// ---------------- top-k (bitonic, matches lax.top_k ties) ----------------
__global__ __launch_bounds__(1024) void topk_kernel(const float* __restrict__ scores,
                                                    int* __restrict__ idx_out) {
    __shared__ float v[2048];
    __shared__ int ixs[2048];
    int tid = threadIdx.x;
    v[tid] = scores[tid];               ixs[tid] = tid;
    v[tid + 1024] = scores[tid + 1024]; ixs[tid + 1024] = tid + 1024;
    __syncthreads();
    for (int k = 2; k <= 2048; k <<= 1) {
        for (int j = k >> 1; j > 0; j >>= 1) {
            #pragma unroll
            for (int half = 0; half < 2; ++half) {
                int i = tid + half * 1024;
                int p = i ^ j;
                if (p > i) {
                    float vi = v[i], vp = v[p];
                    int ii = ixs[i], ip = ixs[p];
                    bool p_before = (vp > vi) || (vp == vi && ip < ii);
                    bool asc = ((i & k) == 0);
                    if (asc ? p_before : !p_before) {
                        v[i] = vp; v[p] = vi; ixs[i] = ip; ixs[p] = ii;
                    }
                }
            }
            __syncthreads();
        }
    }
    for (int k = 2; k <= 512; k <<= 1) {
        for (int j = k >> 1; j > 0; j >>= 1) {
            if (tid < 512) {
                int i = tid, p = i ^ j;
                if (p > i) {
                    int a = ixs[i], b = ixs[p];
                    bool asc = ((i & k) == 0);
                    if (asc ? (b < a) : (b > a)) { ixs[i] = b; ixs[p] = a; }
                }
            }
            __syncthreads();
        }
    }
    if (tid < 512) idx_out[tid] = ixs[tid];
}

// ---------------- gather selected rows (bf16) ----------------
__global__ __launch_bounds__(256) void gather_kernel(const unsigned short* __restrict__ xb,
                                                     const int* __restrict__ idx,
                                                     unsigned short* __restrict__ sel) {
    int i = blockIdx.x * 256 + threadIdx.x;     // SKEEP*128 chunks of 8
    if (i >= SKEEP * 128) return;
    int s = i >> 7, q = i & 127;
    ((u16x8*)sel)[(size_t)s * 128 + q] = ((const u16x8*)xb)[(size_t)idx[s] * 128 + q];
}

// ---------------- assemble q/k1: (nope bf16 [T,512] | rope bf16 [T,1024]) + RoPE -> [T,1536] bf16 ----------------
__global__ __launch_bounds__(256) void assemble_split_kernel(const unsigned short* __restrict__ nope,
                                                             const unsigned short* __restrict__ rope,
                                                             const float* __restrict__ cosT,
                                                             const float* __restrict__ sinT,
                                                             unsigned short* __restrict__ out) {
    int i = blockIdx.x * 256 + threadIdx.x;
    if (i >= TT * HH * 32) return;
    int j = i & 31, h = (i >> 5) & 15, t = i >> 9;
    float c = cosT[t * 32 + j], s = sinT[t * 32 + j];
    size_t ob = (size_t)t * 1536 + h * 96;
    out[ob + j] = nope[(size_t)t * 512 + h * 32 + j];
    float a = bf2f(rope[(size_t)t * 1024 + h * 64 + j]);
    float b = bf2f(rope[(size_t)t * 1024 + h * 64 + 32 + j]);
    out[ob + 32 + j] = f2bf(a * c - b * s);
    out[ob + 64 + j] = f2bf(a * s + b * c);
}

// ---------------- in-place RoPE on bf16 [S,1536] ----------------
__global__ __launch_bounds__(256) void rope_inplace_kernel(unsigned short* __restrict__ buf,
                                                           const float* __restrict__ cosT,
                                                           const float* __restrict__ sinT, int S) {
    int i = blockIdx.x * 256 + threadIdx.x;
    if (i >= S * HH * 32) return;
    int j = i & 31, h = (i >> 5) & 15, t = i >> 9;
    float c = cosT[t * 32 + j], s = sinT[t * 32 + j];
    unsigned short* p = buf + (size_t)t * 1536 + h * 96;
    float a = bf2f(p[32 + j]), b = bf2f(p[64 + j]);
    p[32 + j] = f2bf(a * c - b * s);
    p[64 + j] = f2bf(a * s + b * c);
}

// ---------------- fused 3-branch MFMA flash attention ----------------
// grid (T/64, H), 256 threads (4 waves x 16 q-rows). Writes gated sum as bf16 [T,1536].
__global__ __launch_bounds__(256) void fused_attn_kernel(const unsigned short* __restrict__ qf,
                                                         const unsigned short* __restrict__ k1,
                                                         const unsigned short* __restrict__ v1,
                                                         const unsigned short* __restrict__ ksel,
                                                         const unsigned short* __restrict__ vsel,
                                                         const unsigned short* __restrict__ kw,
                                                         const unsigned short* __restrict__ vw,
                                                         const float* __restrict__ gate,
                                                         unsigned short* __restrict__ ob) {
    __shared__ unsigned short Ks[32 * 96];        // [key][d]
    __shared__ unsigned short Vt[96 * 32];        // [d][key]
    __shared__ unsigned short Ps[4][16 * 40];     // per-wave P [q][k], stride 40
    const int h = blockIdx.y, t0 = blockIdx.x * 64;
    const int tid = threadIdx.x, wave = tid >> 6, lane = tid & 63;
    const int lr = lane & 15, lg = lane >> 4;
    const float SCALE = 0.10206207261596575f;     // 1/sqrt(96)

    bf16x8 qfrag[3];
    {
        const unsigned short* qp = qf + (size_t)(t0 + wave * 16 + lr) * 1536 + h * 96 + lg * 8;
        qfrag[0] = *(const bf16x8*)qp;
        qfrag[1] = *(const bf16x8*)(qp + 32);
        qfrag[2] = *(const bf16x8*)(qp + 64);
    }
    float outv[6][4];
    #pragma unroll
    for (int j = 0; j < 6; ++j)
        #pragma unroll
        for (int r = 0; r < 4; ++r) outv[j][r] = 0.f;

    for (int b = 0; b < 3; ++b) {
        const unsigned short* Kp = (b == 0) ? k1 : ((b == 1) ? ksel : kw);
        const unsigned short* Vp = (b == 0) ? v1 : ((b == 1) ? vsel : vw);
        const int nk = (b == 1) ? SKEEP : (t0 + 64);
        const bool causal = (b != 1);
        f32x4 oacc[6];
        #pragma unroll
        for (int j = 0; j < 6; ++j) oacc[j] = (f32x4){0.f, 0.f, 0.f, 0.f};
        float m[4], l[4];
        #pragma unroll
        for (int r = 0; r < 4; ++r) { m[r] = -1e30f; l[r] = 0.f; }

        for (int k0 = 0; k0 < nk; k0 += 32) {
            // stage K tile (row-major) via async global->LDS
            #pragma unroll
            for (int rep = 0; rep < 2; ++rep) {
                if (rep == 0 || tid < 128) {
                    int cc = tid + rep * 256;                 // 384 chunks of 8 bf16
                    int k = cc / 12, off = (cc % 12) * 8;
                    GLOAD16(Kp + (size_t)(k0 + k) * 1536 + h * 96 + off, &Ks[cc * 8]);
                }
            }
            // stage V tile transposed (reg staged)
            #pragma unroll
            for (int rep = 0; rep < 2; ++rep) {
                if (rep == 0 || tid < 128) {
                    int cc = tid + rep * 256;
                    int k = cc / 12, d0 = (cc % 12) * 8;
                    u16x8 v = *(const u16x8*)(Vp + (size_t)(k0 + k) * 1536 + h * 96 + d0);
                    #pragma unroll
                    for (int j = 0; j < 8; ++j) Vt[(d0 + j) * 32 + k] = v[j];
                }
            }
            __syncthreads();
            // QK^T: S = Q(16x96) . K^T -> 16x32
            f32x4 s0 = (f32x4){0.f, 0.f, 0.f, 0.f}, s1 = s0;
            #pragma unroll
            for (int ds = 0; ds < 3; ++ds) {
                bf16x8 kb0 = *(const bf16x8*)&Ks[lr * 96 + ds * 32 + lg * 8];
                bf16x8 kb1 = *(const bf16x8*)&Ks[(16 + lr) * 96 + ds * 32 + lg * 8];
                s0 = __builtin_amdgcn_mfma_f32_16x16x32_bf16(qfrag[ds], kb0, s0, 0, 0, 0);
                s1 = __builtin_amdgcn_mfma_f32_16x16x32_bf16(qfrag[ds], kb1, s1, 0, 0, 0);
            }
            // online softmax per q-row (rows lg*4+r, keys across lr lanes)
            #pragma unroll
            for (int r = 0; r < 4; ++r) {
                float a0 = s0[r] * SCALE, a1 = s1[r] * SCALE;
                if (causal) {
                    int q = t0 + wave * 16 + lg * 4 + r;
                    if (k0 + lr > q)      a0 = -1e30f;
                    if (k0 + 16 + lr > q) a1 = -1e30f;
                }
                float cur = fmaxf(a0, a1);
                cur = fmaxf(cur, __shfl_xor(cur, 1));
                cur = fmaxf(cur, __shfl_xor(cur, 2));
                cur = fmaxf(cur, __shfl_xor(cur, 4));
                cur = fmaxf(cur, __shfl_xor(cur, 8));
                float mn = fmaxf(m[r], cur);
                float alpha = __expf(m[r] - mn);
                m[r] = mn;
                float p0 = __expf(a0 - mn), p1 = __expf(a1 - mn);
                float ps = p0 + p1;
                ps += __shfl_xor(ps, 1);
                ps += __shfl_xor(ps, 2);
                ps += __shfl_xor(ps, 4);
                ps += __shfl_xor(ps, 8);
                l[r] = l[r] * alpha + ps;
                #pragma unroll
                for (int j = 0; j < 6; ++j) oacc[j][r] *= alpha;
                Ps[wave][(lg * 4 + r) * 40 + lr]      = f2bf(p0);
                Ps[wave][(lg * 4 + r) * 40 + 16 + lr] = f2bf(p1);
            }
            // PV: O += P(16x32) . V(32x96)
            bf16x8 pfrag = *(const bf16x8*)&Ps[wave][lr * 40 + lg * 8];
            #pragma unroll
            for (int j = 0; j < 6; ++j) {
                bf16x8 vb = *(const bf16x8*)&Vt[(j * 16 + lr) * 32 + lg * 8];
                oacc[j] = __builtin_amdgcn_mfma_f32_16x16x32_bf16(pfrag, vb, oacc[j], 0, 0, 0);
            }
            __syncthreads();
        }
        float g = gate[b];
        #pragma unroll
        for (int r = 0; r < 4; ++r) {
            float wgt = g / l[r];
            #pragma unroll
            for (int j = 0; j < 6; ++j) outv[j][r] += oacc[j][r] * wgt;
        }
    }
    #pragma unroll
    for (int r = 0; r < 4; ++r) {
        size_t base = (size_t)(t0 + wave * 16 + lg * 4 + r) * 1536 + h * 96;
        #pragma unroll
        for (int j = 0; j < 6; ++j) ob[base + j * 16 + lr] = f2bf(outv[j][r]);
    }
}

// ---------------- launch ----------------
extern "C" void kernel_launch(void* const* d_in, const int* in_sizes, int n_in,
                              void* d_out, int out_size, void* d_ws, size_t ws_size,
                              hipStream_t stream) {
    const float* x        = (const float*)d_in[0];
    const float* w_cq     = (const float*)d_in[1];
    const float* q_scale  = (const float*)d_in[2];
    const float* w_dq_n   = (const float*)d_in[3];
    const float* w_dq_r   = (const float*)d_in[4];
    const float* w_ckv    = (const float*)d_in[5];
    const float* kv_scale = (const float*)d_in[6];
    const float* w_dk_n   = (const float*)d_in[7];
    const float* w_dv     = (const float*)d_in[8];
    const float* w_k_r    = (const float*)d_in[9];
    const float* w_imp    = (const float*)d_in[10];
    const float* b_imp    = (const float*)d_in[11];
    const float* w_sel_k  = (const float*)d_in[12];
    const float* w_sel_v  = (const float*)d_in[13];
    const float* w_win_k  = (const float*)d_in[14];
    const float* w_win_v  = (const float*)d_in[15];
    const float* w_gate   = (const float*)d_in[16];
    const float* b_gate   = (const float*)d_in[17];
    const float* w_proj   = (const float*)d_in[18];
    float* out = (float*)d_out;
    char* ws = (char*)d_ws;

    float* cosT   = (float*)(ws + B_COS);
    float* sinT   = (float*)(ws + B_SIN);
    unsigned short* xb     = (unsigned short*)(ws + B_XB);
    unsigned short* wCqT   = (unsigned short*)(ws + B_WCQT);
    unsigned short* wDqNT  = (unsigned short*)(ws + B_WDQN);
    unsigned short* wDqRT  = (unsigned short*)(ws + B_WDQR);
    unsigned short* wCkvT  = (unsigned short*)(ws + B_WCKVT);
    unsigned short* wDkNT  = (unsigned short*)(ws + B_WDKN);
    unsigned short* wDvT   = (unsigned short*)(ws + B_WDVT);
    unsigned short* wKrT   = (unsigned short*)(ws + B_WKRT);
    unsigned short* wSelKT = (unsigned short*)(ws + B_WSELK);
    unsigned short* wSelVT = (unsigned short*)(ws + B_WSELV);
    unsigned short* wWinKT = (unsigned short*)(ws + B_WWINK);
    unsigned short* wWinVT = (unsigned short*)(ws + B_WWINV);
    unsigned short* wProjT = (unsigned short*)(ws + B_WPROJ);
    float* qlatf  = (float*)(ws + B_QLATF);
    float* kvlatf = (float*)(ws + B_KVLATF);
    unsigned short* qlatb  = (unsigned short*)(ws + B_QLATB);
    unsigned short* kvlatb = (unsigned short*)(ws + B_KVLATB);
    float* gacc   = (float*)(ws + B_GACC);
    float* gate   = (float*)(ws + B_GATE);
    float* score  = (float*)(ws + B_SCORE);
    int*   idx    = (int*)(ws + B_IDX);
    unsigned short* selxb  = (unsigned short*)(ws + B_SELXB);
    unsigned short* flatn  = (unsigned short*)(ws + B_FLATN);
    unsigned short* flatr  = (unsigned short*)(ws + B_FLATR);
    unsigned short* qfb    = (unsigned short*)(ws + B_QFB);
    unsigned short* k1b    = (unsigned short*)(ws + B_K1B);
    unsigned short* v1b    = (unsigned short*)(ws + B_V1B);
    unsigned short* kwb    = (unsigned short*)(ws + B_KWB);
    unsigned short* vwb    = (unsigned short*)(ws + B_VWB);
    unsigned short* ksb    = (unsigned short*)(ws + B_KSB);
    unsigned short* vsb    = (unsigned short*)(ws + B_VSB);
    unsigned short* ob     = (unsigned short*)(ws + B_OB);

    // 0) tables, zero, converts
    rope_table_kernel<<<dim3(256), dim3(256), 0, stream>>>(cosT, sinT);
    zero_gacc_kernel<<<dim3(1), dim3(64), 0, stream>>>(gacc);
    convert_kernel<<<dim3(2048), dim3(256), 0, stream>>>(x, xb, TT * CC / 4);
    tconv_kernel<<<dim3(4, 32),  dim3(256), 0, stream>>>(w_cq,    wCqT,   1024, 96);
    tconv_kernel<<<dim3(16, 3),  dim3(256), 0, stream>>>(w_dq_n,  wDqNT,  96,   512);
    tconv_kernel<<<dim3(32, 3),  dim3(256), 0, stream>>>(w_dq_r,  wDqRT,  96,   1024);
    tconv_kernel<<<dim3(4, 32),  dim3(256), 0, stream>>>(w_ckv,   wCkvT,  1024, 32);
    tconv_kernel<<<dim3(16, 1),  dim3(256), 0, stream>>>(w_dk_n,  wDkNT,  32,   512);
    tconv_kernel<<<dim3(48, 1),  dim3(256), 0, stream>>>(w_dv,    wDvT,   32,   1536);
    tconv_kernel<<<dim3(32, 1),  dim3(256), 0, stream>>>(w_k_r,   wKrT,   32,   1024);
    tconv_kernel<<<dim3(48, 32), dim3(256), 0, stream>>>(w_sel_k, wSelKT, 1024, 1536);
    tconv_kernel<<<dim3(48, 32), dim3(256), 0, stream>>>(w_sel_v, wSelVT, 1024, 1536);
    tconv_kernel<<<dim3(48, 32), dim3(256), 0, stream>>>(w_win_k, wWinKT, 1024, 1536);
    tconv_kernel<<<dim3(48, 32), dim3(256), 0, stream>>>(w_win_v, wWinVT, 1024, 1536);
    tconv_kernel<<<dim3(32, 48), dim3(256), 0, stream>>>(w_proj,  wProjT, 1536, 1024);

    // 1) latents + RMS
    gemm_bf16<float><<<dim3(1, 16), dim3(256), 0, stream>>>(xb, wCqT,  qlatf,  TT, 96, CC);
    gemm_bf16<float><<<dim3(1, 16), dim3(256), 0, stream>>>(xb, wCkvT, kvlatf, TT, 32, CC);
    rms_kernel<<<dim3(TT), dim3(64), 0, stream>>>(qlatf,  qlatb,  q_scale,  96);
    rms_kernel<<<dim3(TT), dim3(64), 0, stream>>>(kvlatf, kvlatb, kv_scale, 32);

    // 2) gate + scores + topk + gather
    gate_scores_kernel<<<dim3(TT), dim3(256), 0, stream>>>(x, w_gate, w_imp, b_imp, gacc, score);
    gate_finalize_kernel<<<dim3(1), dim3(64), 0, stream>>>(gacc, b_gate, gate);
    topk_kernel<<<dim3(1), dim3(1024), 0, stream>>>(score, idx);
    gather_kernel<<<dim3(SKEEP * 128 / 256), dim3(256), 0, stream>>>(xb, idx, selxb);

    // 3) Q assembly
    gemm_bf16<unsigned short><<<dim3(4, 16), dim3(256), 0, stream>>>(qlatb, wDqNT, flatn, TT, 512, 96);
    gemm_bf16<unsigned short><<<dim3(8, 16), dim3(256), 0, stream>>>(qlatb, wDqRT, flatr, TT, 1024, 96);
    assemble_split_kernel<<<dim3(TT * HH * 32 / 256), dim3(256), 0, stream>>>(flatn, flatr, cosT, sinT, qfb);

    // 4) branch-1 K/V
    gemm_bf16<unsigned short><<<dim3(4, 16), dim3(256), 0, stream>>>(kvlatb, wDkNT, flatn, TT, 512, 32);
    gemm_bf16<unsigned short><<<dim3(8, 16), dim3(256), 0, stream>>>(kvlatb, wKrT, flatr, TT, 1024, 32);
    assemble_split_kernel<<<dim3(TT * HH * 32 / 256), dim3(256), 0, stream>>>(flatn, flatr, cosT, sinT, k1b);
    gemm_bf16<unsigned short><<<dim3(12, 16), dim3(256), 0, stream>>>(kvlatb, wDvT, v1b, TT, 1536, 32);

    // 5) window branch K/V
    gemm_bf16<unsigned short><<<dim3(12, 16), dim3(256), 0, stream>>>(xb, wWinKT, kwb, TT, 1536, CC);
    rope_inplace_kernel<<<dim3(TT * HH * 32 / 256), dim3(256), 0, stream>>>(kwb, cosT, sinT, TT);
    gemm_bf16<unsigned short><<<dim3(12, 16), dim3(256), 0, stream>>>(xb, wWinVT, vwb, TT, 1536, CC);

    // 6) selected branch K/V
    gemm_bf16<unsigned short><<<dim3(12, 4), dim3(256), 0, stream>>>(selxb, wSelKT, ksb, SKEEP, 1536, CC);
    rope_inplace_kernel<<<dim3(SKEEP * HH * 32 / 256), dim3(256), 0, stream>>>(ksb, cosT, sinT, SKEEP);
    gemm_bf16<unsigned short><<<dim3(12, 4), dim3(256), 0, stream>>>(selxb, wSelVT, vsb, SKEEP, 1536, CC);

    // 7) fused 3-branch attention -> ob (bf16, gated sum)
    fused_attn_kernel<<<dim3(TT / 64, HH), dim3(256), 0, stream>>>(
        qfb, k1b, v1b, ksb, vsb, kwb, vwb, gate, ob);

    // 8) output projection
    gemm_bf16<float><<<dim3(8, 16), dim3(256), 0, stream>>>(ob, wProjT, out, TT, CC, 1536);
}

// Round 5
// 565.397 us; speedup vs baseline: 4.3475x; 1.5314x over previous
//
#include <hip/hip_runtime.h>
#include <cmath>

#define TT 2048
#define CC 1024
#define HH 16
#define SKEEP 512

typedef __attribute__((ext_vector_type(8))) short bf16x8;
typedef __attribute__((ext_vector_type(4))) float f32x4;
typedef __attribute__((ext_vector_type(8))) unsigned short u16x8;

__device__ __forceinline__ unsigned short f2bf(float f) {
    union { float f; unsigned int u; } v; v.f = f;
    unsigned int r = v.u + 0x7fffu + ((v.u >> 16) & 1u);
    return (unsigned short)(r >> 16);
}
__device__ __forceinline__ float bf2f(unsigned short b) {
    union { unsigned int u; float f; } v; v.u = ((unsigned int)b) << 16;
    return v.f;
}

#define GLOAD16(gp, lp) __builtin_amdgcn_global_load_lds( \
    (const __attribute__((address_space(1))) void*)(gp),  \
    (__attribute__((address_space(3))) void*)(lp), 16, 0, 0)

// ---------------- workspace byte offsets (~71 MB) ----------------
static constexpr size_t B_COS   = 0;
static constexpr size_t B_SIN   = B_COS   + 262144;
static constexpr size_t B_XB    = B_SIN   + 262144;         // 2048*1024 bf16
static constexpr size_t B_WCQT  = B_XB    + 4194304;        // 128x1024 (pad 96->128)
static constexpr size_t B_WDQN  = B_WCQT  + 262144;         // 512x96
static constexpr size_t B_WDQR  = B_WDQN  + 98304;          // 1024x96
static constexpr size_t B_WCKVT = B_WDQR  + 196608;         // 128x1024 (pad 32->128)
static constexpr size_t B_WDKN  = B_WCKVT + 262144;         // 512x32
static constexpr size_t B_WDVT  = B_WDKN  + 32768;          // 1536x32
static constexpr size_t B_WKRT  = B_WDVT  + 98304;          // 1024x32
static constexpr size_t B_WSELK = B_WKRT  + 65536;          // 1536x1024
static constexpr size_t B_WSELV = B_WSELK + 3145728;
static constexpr size_t B_WWINK = B_WSELV + 3145728;
static constexpr size_t B_WWINV = B_WWINK + 3145728;
static constexpr size_t B_WPROJ = B_WWINV + 3145728;        // 1024x1536
static constexpr size_t B_QLATF = B_WPROJ + 3145728;        // 2048*96 f32
static constexpr size_t B_KVLATF= B_QLATF + 786432;         // 2048*32 f32
static constexpr size_t B_QLATB = B_KVLATF+ 262144;         // 2048*96 bf16
static constexpr size_t B_KVLATB= B_QLATB + 393216;         // 2048*32 bf16
static constexpr size_t B_GPART = B_KVLATB+ 131072;         // 2048*3 f32 gate partials
static constexpr size_t B_GATE  = B_GPART + 24576;
static constexpr size_t B_SCORE = B_GATE  + 256;
static constexpr size_t B_IDX   = B_SCORE + 8192;
static constexpr size_t B_SELXB = B_IDX   + 2048;           // 512*1024 bf16
static constexpr size_t B_FLATN = B_SELXB + 1048576;        // 2048*512 bf16
static constexpr size_t B_FLATR = B_FLATN + 2097152;        // 2048*1024 bf16
static constexpr size_t B_QFB   = B_FLATR + 4194304;        // 2048*1536 bf16
static constexpr size_t B_K1B   = B_QFB   + 6291456;        // K1 [2048][1536]
static constexpr size_t B_VT1   = B_K1B   + 6291456;        // V1^T [1536][2048]
static constexpr size_t B_KWB   = B_VT1   + 6291456;        // Kwin [2048][1536]
static constexpr size_t B_VTW   = B_KWB   + 6291456;        // Vwin^T [1536][2048]
static constexpr size_t B_KSB   = B_VTW   + 6291456;        // Ksel [512][1536]
static constexpr size_t B_VTS   = B_KSB   + 1572864;        // Vsel^T [1536][512]
static constexpr size_t B_OB    = B_VTS   + 1572864;        // o_comb [2048][1536] bf16

// ---------------- RoPE tables ----------------
__global__ void rope_table_kernel(float* __restrict__ cosT, float* __restrict__ sinT) {
    int i = blockIdx.x * blockDim.x + threadIdx.x;
    if (i >= TT * 32) return;
    int t = i >> 5, j = i & 31;
    float inv = (float)exp(-(double)j * (9.210340371976184 / 32.0));
    float f = (float)t * inv;
    cosT[i] = (float)cos((double)f);
    sinT[i] = (float)sin((double)f);
}

// ---------------- f32 -> bf16 convert ----------------
__global__ __launch_bounds__(256) void convert_kernel(const float* __restrict__ src,
                                                      unsigned short* __restrict__ dst, int n4) {
    int i = blockIdx.x * 256 + threadIdx.x;
    if (i >= n4) return;
    float4 v = ((const float4*)src)[i];
    ushort4 o;
    o.x = f2bf(v.x); o.y = f2bf(v.y); o.z = f2bf(v.z); o.w = f2bf(v.w);
    ((ushort4*)dst)[i] = o;
}

// ---------------- transpose-convert: f32 [K,N] -> bf16 [NP,K] (pad rows zero) ----------------
__global__ __launch_bounds__(256) void tconv_kernel(const float* __restrict__ src,
                                                    unsigned short* __restrict__ dst,
                                                    int K, int N) {
    __shared__ float tile[32][33];
    int n0 = blockIdx.x * 32, k0 = blockIdx.y * 32;
    int tx = threadIdx.x & 31, ty = threadIdx.x >> 5;
    #pragma unroll
    for (int r = ty; r < 32; r += 8) {
        float v = 0.f;
        if (n0 + tx < N) v = src[(size_t)(k0 + r) * N + n0 + tx];
        tile[r][tx] = v;
    }
    __syncthreads();
    #pragma unroll
    for (int r = ty; r < 32; r += 8)
        dst[(size_t)(n0 + r) * K + k0 + tx] = f2bf(tile[tx][r]);
}

// ---------------- bf16 MFMA GEMM 128x128: C[M,N] = A[M,K] * BT[N,K]^T ----------------
template<typename OUTT>
__global__ __launch_bounds__(256) void gemm_bf16(const unsigned short* __restrict__ A,
                                                 const unsigned short* __restrict__ BT,
                                                 OUTT* __restrict__ C,
                                                 int M, int N, int K) {
    __shared__ unsigned short As[128 * 32];
    __shared__ unsigned short Bs[128 * 32];
    const int tid = threadIdx.x;
    const int m0 = blockIdx.y * 128, n0 = blockIdx.x * 128;
    const int lane = tid & 63, lr = lane & 15, lg = lane >> 4;
    const int wave = tid >> 6;
    const int wm = (wave & 1) * 64, wn = (wave >> 1) * 64;
    f32x4 acc[4][4];
    #pragma unroll
    for (int i = 0; i < 4; ++i)
        #pragma unroll
        for (int j = 0; j < 4; ++j) acc[i][j] = (f32x4){0.f, 0.f, 0.f, 0.f};
    const int ar = tid >> 2, ak = (tid & 3) * 8;
    const unsigned short* ga = A + (size_t)(m0 + ar) * K + ak;
    const unsigned short* gb = BT + (size_t)(n0 + ar) * K + ak;
    for (int k0 = 0; k0 < K; k0 += 32) {
        GLOAD16(ga + k0, &As[tid * 8]);
        GLOAD16(ga + (size_t)64 * K + k0, &As[2048 + tid * 8]);
        GLOAD16(gb + k0, &Bs[tid * 8]);
        GLOAD16(gb + (size_t)64 * K + k0, &Bs[2048 + tid * 8]);
        __syncthreads();
        bf16x8 af[4], bfr[4];
        #pragma unroll
        for (int i = 0; i < 4; ++i) af[i] = *(const bf16x8*)&As[(wm + i * 16 + lr) * 32 + lg * 8];
        #pragma unroll
        for (int j = 0; j < 4; ++j) bfr[j] = *(const bf16x8*)&Bs[(wn + j * 16 + lr) * 32 + lg * 8];
        #pragma unroll
        for (int i = 0; i < 4; ++i)
            #pragma unroll
            for (int j = 0; j < 4; ++j)
                acc[i][j] = __builtin_amdgcn_mfma_f32_16x16x32_bf16(af[i], bfr[j], acc[i][j], 0, 0, 0);
        __syncthreads();
    }
    #pragma unroll
    for (int i = 0; i < 4; ++i) {
        #pragma unroll
        for (int r = 0; r < 4; ++r) {
            int row = m0 + wm + i * 16 + lg * 4 + r;
            #pragma unroll
            for (int j = 0; j < 4; ++j) {
                int col = n0 + wn + j * 16 + lr;
                if (col < N) {
                    float v = acc[i][j][r];
                    if constexpr (__is_same(OUTT, float)) C[(size_t)row * N + col] = v;
                    else                                  C[(size_t)row * N + col] = f2bf(v);
                }
            }
        }
    }
}

// ---------------- bf16 MFMA GEMM 64x128 tile (better CU coverage for short M) ----------------
template<typename OUTT>
__global__ __launch_bounds__(256) void gemm_bf16_64(const unsigned short* __restrict__ A,
                                                    const unsigned short* __restrict__ BT,
                                                    OUTT* __restrict__ C,
                                                    int M, int N, int K) {
    __shared__ unsigned short As[64 * 32];
    __shared__ unsigned short Bs[128 * 32];
    const int tid = threadIdx.x;
    const int m0 = blockIdx.y * 64, n0 = blockIdx.x * 128;
    const int lane = tid & 63, lr = lane & 15, lg = lane >> 4;
    const int wave = tid >> 6;
    const int wn = wave * 32;
    f32x4 acc[4][2];
    #pragma unroll
    for (int i = 0; i < 4; ++i)
        #pragma unroll
        for (int j = 0; j < 2; ++j) acc[i][j] = (f32x4){0.f, 0.f, 0.f, 0.f};
    const int ar = tid >> 2, ak = (tid & 3) * 8;   // A: 64 rows x 4 chunks
    const unsigned short* ga = A + (size_t)(m0 + ar) * K + ak;
    const unsigned short* gb = BT + (size_t)(n0 + ar) * K + ak;
    for (int k0 = 0; k0 < K; k0 += 32) {
        GLOAD16(ga + k0, &As[tid * 8]);
        GLOAD16(gb + k0, &Bs[tid * 8]);
        GLOAD16(gb + (size_t)64 * K + k0, &Bs[2048 + tid * 8]);
        __syncthreads();
        bf16x8 af[4], bfr[2];
        #pragma unroll
        for (int i = 0; i < 4; ++i) af[i] = *(const bf16x8*)&As[(i * 16 + lr) * 32 + lg * 8];
        #pragma unroll
        for (int j = 0; j < 2; ++j) bfr[j] = *(const bf16x8*)&Bs[(wn + j * 16 + lr) * 32 + lg * 8];
        #pragma unroll
        for (int i = 0; i < 4; ++i)
            #pragma unroll
            for (int j = 0; j < 2; ++j)
                acc[i][j] = __builtin_amdgcn_mfma_f32_16x16x32_bf16(af[i], bfr[j], acc[i][j], 0, 0, 0);
        __syncthreads();
    }
    #pragma unroll
    for (int i = 0; i < 4; ++i) {
        #pragma unroll
        for (int r = 0; r < 4; ++r) {
            int row = m0 + i * 16 + lg * 4 + r;
            #pragma unroll
            for (int j = 0; j < 2; ++j) {
                int col = n0 + wn + j * 16 + lr;
                if (col < N) {
                    float v = acc[i][j][r];
                    if constexpr (__is_same(OUTT, float)) C[(size_t)row * N + col] = v;
                    else                                  C[(size_t)row * N + col] = f2bf(v);
                }
            }
        }
    }
}

// ---------------- RMSNorm: f32 in -> bf16 out ----------------
__global__ __launch_bounds__(64) void rms_kernel(const float* __restrict__ in,
                                                 unsigned short* __restrict__ outb,
                                                 const float* __restrict__ scale, int D) {
    int t = blockIdx.x, lane = threadIdx.x;
    const float* row = in + (size_t)t * D;
    float ss = 0.f;
    for (int d = lane; d < D; d += 64) { float v = row[d]; ss += v * v; }
    #pragma unroll
    for (int o = 32; o > 0; o >>= 1) ss += __shfl_xor(ss, o);
    float rs = 1.0f / sqrtf(ss / (float)D + 1e-6f);
    for (int d = lane; d < D; d += 64) outb[(size_t)t * D + d] = f2bf(row[d] * rs * scale[d]);
}

// ---------------- gate partials + importance scores (no atomics) ----------------
__global__ __launch_bounds__(256) void gate_scores_kernel(const float* __restrict__ x,
                                                          const float* __restrict__ w_gate,
                                                          const float* __restrict__ w_imp,
                                                          const float* __restrict__ b_imp,
                                                          float* __restrict__ gpart,
                                                          float* __restrict__ scores) {
    int t = blockIdx.x;
    const float* xr = x + (size_t)t * CC;
    float g0 = 0, g1 = 0, g2 = 0, si = 0;
    for (int c = threadIdx.x; c < CC; c += 256) {
        float xv = xr[c];
        g0 += xv * w_gate[c * 3 + 0];
        g1 += xv * w_gate[c * 3 + 1];
        g2 += xv * w_gate[c * 3 + 2];
        si += xv * w_imp[c];
    }
    #pragma unroll
    for (int o = 32; o > 0; o >>= 1) {
        g0 += __shfl_xor(g0, o); g1 += __shfl_xor(g1, o);
        g2 += __shfl_xor(g2, o); si += __shfl_xor(si, o);
    }
    __shared__ float red[4][4];
    int w_ = threadIdx.x >> 6, lane = threadIdx.x & 63;
    if (lane == 0) { red[w_][0] = g0; red[w_][1] = g1; red[w_][2] = g2; red[w_][3] = si; }
    __syncthreads();
    if (threadIdx.x == 0) {
        gpart[t * 3 + 0] = red[0][0] + red[1][0] + red[2][0] + red[3][0];
        gpart[t * 3 + 1] = red[0][1] + red[1][1] + red[2][1] + red[3][1];
        gpart[t * 3 + 2] = red[0][2] + red[1][2] + red[2][2] + red[3][2];
        scores[t] = red[0][3] + red[1][3] + red[2][3] + red[3][3] + b_imp[0];
    }
}

// deterministic fixed-order reduction of gpart[2048][3] -> gate[3]
__global__ __launch_bounds__(256) void gate_finalize_kernel(const float* __restrict__ gpart,
                                                            const float* __restrict__ b_gate,
                                                            float* __restrict__ gate) {
    __shared__ float red[256][3];
    int tid = threadIdx.x;
    float a0 = 0, a1 = 0, a2 = 0;
    #pragma unroll
    for (int i = 0; i < 8; ++i) {
        int t = tid * 8 + i;
        a0 += gpart[t * 3 + 0];
        a1 += gpart[t * 3 + 1];
        a2 += gpart[t * 3 + 2];
    }
    red[tid][0] = a0; red[tid][1] = a1; red[tid][2] = a2;
    __syncthreads();
    for (int s = 128; s > 0; s >>= 1) {
        if (tid < s) {
            red[tid][0] += red[tid + s][0];
            red[tid][1] += red[tid + s][1];
            red[tid][2] += red[tid + s][2];
        }
        __syncthreads();
    }
    if (tid == 0) {
        float g0 = red[0][0] / (float)TT + b_gate[0];
        float g1 = red[0][1] / (float)TT + b_gate[1];
        float g2 = red[0][2] / (float)TT + b_gate[2];
        float mx = fmaxf(g0, fmaxf(g1, g2));
        float e0 = __expf(g0 - mx), e1 = __expf(g1 - mx), e2 = __expf(g2 - mx);
        float s = e0 + e1 + e2;
        gate[0] = e0 / s; gate[1] = e1 / s; gate[2] = e2 / s;
    }
}

// ---------------- top-k (bitonic, matches lax.top_k ties) ----------------
__global__ __launch_bounds__(1024) void topk_kernel(const float* __restrict__ scores,
                                                    int* __restrict__ idx_out) {
    __shared__ float v[2048];
    __shared__ int ixs[2048];
    int tid = threadIdx.x;
    v[tid] = scores[tid];               ixs[tid] = tid;
    v[tid + 1024] = scores[tid + 1024]; ixs[tid + 1024] = tid + 1024;
    __syncthreads();
    for (int k = 2; k <= 2048; k <<= 1) {
        for (int j = k >> 1; j > 0; j >>= 1) {
            #pragma unroll
            for (int half = 0; half < 2; ++half) {
                int i = tid + half * 1024;
                int p = i ^ j;
                if (p > i) {
                    float vi = v[i], vp = v[p];
                    int ii = ixs[i], ip = ixs[p];
                    bool p_before = (vp > vi) || (vp == vi && ip < ii);
                    bool asc = ((i & k) == 0);
                    if (asc ? p_before : !p_before) {
                        v[i] = vp; v[p] = vi; ixs[i] = ip; ixs[p] = ii;
                    }
                }
            }
            __syncthreads();
        }
    }
    for (int k = 2; k <= 512; k <<= 1) {
        for (int j = k >> 1; j > 0; j >>= 1) {
            if (tid < 512) {
                int i = tid, p = i ^ j;
                if (p > i) {
                    int a = ixs[i], b = ixs[p];
                    bool asc = ((i & k) == 0);
                    if (asc ? (b < a) : (b > a)) { ixs[i] = b; ixs[p] = a; }
                }
            }
            __syncthreads();
        }
    }
    if (tid < 512) idx_out[tid] = ixs[tid];
}

// ---------------- gather selected rows (bf16) ----------------
__global__ __launch_bounds__(256) void gather_kernel(const unsigned short* __restrict__ xb,
                                                     const int* __restrict__ idx,
                                                     unsigned short* __restrict__ sel) {
    int i = blockIdx.x * 256 + threadIdx.x;
    if (i >= SKEEP * 128) return;
    int s = i >> 7, q = i & 127;
    ((u16x8*)sel)[(size_t)s * 128 + q] = ((const u16x8*)xb)[(size_t)idx[s] * 128 + q];
}

// ---------------- assemble q/k1 + RoPE ----------------
__global__ __launch_bounds__(256) void assemble_split_kernel(const unsigned short* __restrict__ nope,
                                                             const unsigned short* __restrict__ rope,
                                                             const float* __restrict__ cosT,
                                                             const float* __restrict__ sinT,
                                                             unsigned short* __restrict__ out) {
    int i = blockIdx.x * 256 + threadIdx.x;
    if (i >= TT * HH * 32) return;
    int j = i & 31, h = (i >> 5) & 15, t = i >> 9;
    float c = cosT[t * 32 + j], s = sinT[t * 32 + j];
    size_t ob = (size_t)t * 1536 + h * 96;
    out[ob + j] = nope[(size_t)t * 512 + h * 32 + j];
    float a = bf2f(rope[(size_t)t * 1024 + h * 64 + j]);
    float b = bf2f(rope[(size_t)t * 1024 + h * 64 + 32 + j]);
    out[ob + 32 + j] = f2bf(a * c - b * s);
    out[ob + 64 + j] = f2bf(a * s + b * c);
}

// ---------------- in-place RoPE on bf16 [S,1536] ----------------
__global__ __launch_bounds__(256) void rope_inplace_kernel(unsigned short* __restrict__ buf,
                                                           const float* __restrict__ cosT,
                                                           const float* __restrict__ sinT, int S) {
    int i = blockIdx.x * 256 + threadIdx.x;
    if (i >= S * HH * 32) return;
    int j = i & 31, h = (i >> 5) & 15, t = i >> 9;
    float c = cosT[t * 32 + j], s = sinT[t * 32 + j];
    unsigned short* p = buf + (size_t)t * 1536 + h * 96;
    float a = bf2f(p[32 + j]), b = bf2f(p[64 + j]);
    p[32 + j] = f2bf(a * c - b * s);
    p[64 + j] = f2bf(a * s + b * c);
}

// ---------------- fused 3-branch MFMA flash attention (single-buffer, 2-barrier) ----------------
// grid (16,16) blocks of 512 threads (8 waves x 16 q-rows = 128 queries/block).
// K row-major [T][1536]; V transposed [1536][Tv].
#define BQ 128
#define KVB 64
__global__ __launch_bounds__(512) void fused_attn_kernel(
        const unsigned short* __restrict__ qf,
        const unsigned short* __restrict__ k1, const unsigned short* __restrict__ vt1,
        const unsigned short* __restrict__ ksel, const unsigned short* __restrict__ vts,
        const unsigned short* __restrict__ kw, const unsigned short* __restrict__ vtw,
        const float* __restrict__ gate, unsigned short* __restrict__ ob) {
    __shared__ unsigned short Ks[KVB * 96];      // [key][d]
    __shared__ unsigned short Vs[96 * KVB];      // [d][key], XOR-swizzled 16B chunks
    __shared__ unsigned short Ps[8][16 * 72];    // per-wave P [q][k], stride 72
    const int orig = blockIdx.y * gridDim.x + blockIdx.x;     // 256 blocks
    const int virt = (orig & 7) * 32 + (orig >> 3);           // XCD-contiguous (2 heads/XCD)
    const int h = virt >> 4, tt = virt & 15;
    const int t0 = tt * BQ;
    const int tid = threadIdx.x, wave = tid >> 6, lane = tid & 63;
    const int lr = lane & 15, lg = lane >> 4;
    const float SCALE = 0.10206207261596575f;    // 1/sqrt(96)

    // Q fragments held in registers for all branches
    bf16x8 qfrag[3];
    {
        const unsigned short* qp = qf + (size_t)(t0 + wave * 16 + lr) * 1536 + h * 96 + lg * 8;
        qfrag[0] = *(const bf16x8*)qp;
        qfrag[1] = *(const bf16x8*)(qp + 32);
        qfrag[2] = *(const bf16x8*)(qp + 64);
    }
    float outv[6][4];
    #pragma unroll
    for (int j = 0; j < 6; ++j)
        #pragma unroll
        for (int r = 0; r < 4; ++r) outv[j][r] = 0.f;

    // staging: K 768 chunks (64 rows x 12), V 768 chunks (96 rows x 8, src XOR-swizzled)
    auto stage = [&](const unsigned short* Kp, const unsigned short* Vtp, int vstr, int k0) {
        int c = tid;
        GLOAD16(Kp + (size_t)(k0 + c / 12) * 1536 + h * 96 + (c % 12) * 8, &Ks[c * 8]);
        int d = c >> 3, scb = (c & 7) ^ (d & 7);
        GLOAD16(Vtp + (size_t)(h * 96 + d) * vstr + k0 + scb * 8, &Vs[c * 8]);
        if (tid < 256) {
            int c2 = 512 + tid;
            GLOAD16(Kp + (size_t)(k0 + c2 / 12) * 1536 + h * 96 + (c2 % 12) * 8, &Ks[c2 * 8]);
            int d2 = c2 >> 3, scb2 = (c2 & 7) ^ (d2 & 7);
            GLOAD16(Vtp + (size_t)(h * 96 + d2) * vstr + k0 + scb2 * 8, &Vs[c2 * 8]);
        }
    };

    for (int b = 0; b < 3; ++b) {
        const unsigned short* Kp  = (b == 0) ? k1  : ((b == 1) ? ksel : kw);
        const unsigned short* Vtp = (b == 0) ? vt1 : ((b == 1) ? vts  : vtw);
        const int vstr = (b == 1) ? SKEEP : TT;
        const bool causal = (b != 1);
        const int nt = causal ? ((t0 + BQ) / KVB) : (SKEEP / KVB);
        f32x4 oacc[6];
        #pragma unroll
        for (int j = 0; j < 6; ++j) oacc[j] = (f32x4){0.f, 0.f, 0.f, 0.f};
        float m[4], l[4];
        #pragma unroll
        for (int r = 0; r < 4; ++r) { m[r] = -1e30f; l[r] = 0.f; }

        for (int t = 0; t < nt; ++t) {
            const int k0 = t * KVB;
            stage(Kp, Vtp, vstr, k0);
            __syncthreads();                     // vmcnt(0) drain: tile staged
            const bool active = !causal || (k0 <= t0 + wave * 16 + 15);
            if (active) {
                // QK^T: 16x64 scores per wave
                f32x4 s[4];
                #pragma unroll
                for (int c = 0; c < 4; ++c) s[c] = (f32x4){0.f, 0.f, 0.f, 0.f};
                #pragma unroll
                for (int ds = 0; ds < 3; ++ds) {
                    #pragma unroll
                    for (int c = 0; c < 4; ++c) {
                        bf16x8 kb = *(const bf16x8*)&Ks[(c * 16 + lr) * 96 + ds * 32 + lg * 8];
                        s[c] = __builtin_amdgcn_mfma_f32_16x16x32_bf16(qfrag[ds], kb, s[c], 0, 0, 0);
                    }
                }
                // online softmax (rows lg*4+r; 16 key-lanes via lr)
                #pragma unroll
                for (int r = 0; r < 4; ++r) {
                    const int qrow = t0 + wave * 16 + lg * 4 + r;
                    float a0 = s[0][r] * SCALE, a1 = s[1][r] * SCALE;
                    float a2 = s[2][r] * SCALE, a3 = s[3][r] * SCALE;
                    if (causal) {
                        if (k0 + lr > qrow)      a0 = -1e30f;
                        if (k0 + 16 + lr > qrow) a1 = -1e30f;
                        if (k0 + 32 + lr > qrow) a2 = -1e30f;
                        if (k0 + 48 + lr > qrow) a3 = -1e30f;
                    }
                    float mx = fmaxf(fmaxf(a0, a1), fmaxf(a2, a3));
                    mx = fmaxf(mx, __shfl_xor(mx, 1));
                    mx = fmaxf(mx, __shfl_xor(mx, 2));
                    mx = fmaxf(mx, __shfl_xor(mx, 4));
                    mx = fmaxf(mx, __shfl_xor(mx, 8));
                    float mn = fmaxf(m[r], mx);
                    float alpha = __expf(m[r] - mn);
                    m[r] = mn;
                    float p0 = __expf(a0 - mn), p1 = __expf(a1 - mn);
                    float p2 = __expf(a2 - mn), p3 = __expf(a3 - mn);
                    float ps = (p0 + p1) + (p2 + p3);
                    ps += __shfl_xor(ps, 1);
                    ps += __shfl_xor(ps, 2);
                    ps += __shfl_xor(ps, 4);
                    ps += __shfl_xor(ps, 8);
                    l[r] = l[r] * alpha + ps;
                    #pragma unroll
                    for (int j = 0; j < 6; ++j) oacc[j][r] *= alpha;
                    const int pb = (lg * 4 + r) * 72;
                    Ps[wave][pb + lr]      = f2bf(p0);
                    Ps[wave][pb + 16 + lr] = f2bf(p1);
                    Ps[wave][pb + 32 + lr] = f2bf(p2);
                    Ps[wave][pb + 48 + lr] = f2bf(p3);
                }
                // PV: O += P(16x64) . V(64x96)
                #pragma unroll
                for (int ks = 0; ks < 2; ++ks) {
                    bf16x8 pf = *(const bf16x8*)&Ps[wave][lr * 72 + ks * 32 + lg * 8];
                    #pragma unroll
                    for (int j = 0; j < 6; ++j) {
                        const int d = j * 16 + lr;
                        const int cb = (ks * 4 + lg) ^ (lr & 7);
                        bf16x8 vb = *(const bf16x8*)&Vs[d * 64 + cb * 8];
                        oacc[j] = __builtin_amdgcn_mfma_f32_16x16x32_bf16(pf, vb, oacc[j], 0, 0, 0);
                    }
                }
            }
            __syncthreads();                     // all reads done before next stage overwrites
        }
        const float g = gate[b];
        #pragma unroll
        for (int r = 0; r < 4; ++r) {
            float wgt = g / l[r];
            #pragma unroll
            for (int j = 0; j < 6; ++j) outv[j][r] += oacc[j][r] * wgt;
        }
    }
    #pragma unroll
    for (int r = 0; r < 4; ++r) {
        size_t base = (size_t)(t0 + wave * 16 + lg * 4 + r) * 1536 + h * 96;
        #pragma unroll
        for (int j = 0; j < 6; ++j) ob[base + j * 16 + lr] = f2bf(outv[j][r]);
    }
}

// ---------------- launch ----------------
extern "C" void kernel_launch(void* const* d_in, const int* in_sizes, int n_in,
                              void* d_out, int out_size, void* d_ws, size_t ws_size,
                              hipStream_t stream) {
    const float* x        = (const float*)d_in[0];
    const float* w_cq     = (const float*)d_in[1];
    const float* q_scale  = (const float*)d_in[2];
    const float* w_dq_n   = (const float*)d_in[3];
    const float* w_dq_r   = (const float*)d_in[4];
    const float* w_ckv    = (const float*)d_in[5];
    const float* kv_scale = (const float*)d_in[6];
    const float* w_dk_n   = (const float*)d_in[7];
    const float* w_dv     = (const float*)d_in[8];
    const float* w_k_r    = (const float*)d_in[9];
    const float* w_imp    = (const float*)d_in[10];
    const float* b_imp    = (const float*)d_in[11];
    const float* w_sel_k  = (const float*)d_in[12];
    const float* w_sel_v  = (const float*)d_in[13];
    const float* w_win_k  = (const float*)d_in[14];
    const float* w_win_v  = (const float*)d_in[15];
    const float* w_gate   = (const float*)d_in[16];
    const float* b_gate   = (const float*)d_in[17];
    const float* w_proj   = (const float*)d_in[18];
    float* out = (float*)d_out;
    char* ws = (char*)d_ws;

    float* cosT   = (float*)(ws + B_COS);
    float* sinT   = (float*)(ws + B_SIN);
    unsigned short* xb     = (unsigned short*)(ws + B_XB);
    unsigned short* wCqT   = (unsigned short*)(ws + B_WCQT);
    unsigned short* wDqNT  = (unsigned short*)(ws + B_WDQN);
    unsigned short* wDqRT  = (unsigned short*)(ws + B_WDQR);
    unsigned short* wCkvT  = (unsigned short*)(ws + B_WCKVT);
    unsigned short* wDkNT  = (unsigned short*)(ws + B_WDKN);
    unsigned short* wDvT   = (unsigned short*)(ws + B_WDVT);
    unsigned short* wKrT   = (unsigned short*)(ws + B_WKRT);
    unsigned short* wSelKT = (unsigned short*)(ws + B_WSELK);
    unsigned short* wSelVT = (unsigned short*)(ws + B_WSELV);
    unsigned short* wWinKT = (unsigned short*)(ws + B_WWINK);
    unsigned short* wWinVT = (unsigned short*)(ws + B_WWINV);
    unsigned short* wProjT = (unsigned short*)(ws + B_WPROJ);
    float* qlatf  = (float*)(ws + B_QLATF);
    float* kvlatf = (float*)(ws + B_KVLATF);
    unsigned short* qlatb  = (unsigned short*)(ws + B_QLATB);
    unsigned short* kvlatb = (unsigned short*)(ws + B_KVLATB);
    float* gpart  = (float*)(ws + B_GPART);
    float* gate   = (float*)(ws + B_GATE);
    float* score  = (float*)(ws + B_SCORE);
    int*   idx    = (int*)(ws + B_IDX);
    unsigned short* selxb  = (unsigned short*)(ws + B_SELXB);
    unsigned short* flatn  = (unsigned short*)(ws + B_FLATN);
    unsigned short* flatr  = (unsigned short*)(ws + B_FLATR);
    unsigned short* qfb    = (unsigned short*)(ws + B_QFB);
    unsigned short* k1b    = (unsigned short*)(ws + B_K1B);
    unsigned short* vt1    = (unsigned short*)(ws + B_VT1);
    unsigned short* kwb    = (unsigned short*)(ws + B_KWB);
    unsigned short* vtw    = (unsigned short*)(ws + B_VTW);
    unsigned short* ksb    = (unsigned short*)(ws + B_KSB);
    unsigned short* vts    = (unsigned short*)(ws + B_VTS);
    unsigned short* ob     = (unsigned short*)(ws + B_OB);

    // 0) tables, converts
    rope_table_kernel<<<dim3(256), dim3(256), 0, stream>>>(cosT, sinT);
    convert_kernel<<<dim3(2048), dim3(256), 0, stream>>>(x, xb, TT * CC / 4);
    tconv_kernel<<<dim3(4, 32),  dim3(256), 0, stream>>>(w_cq,    wCqT,   1024, 96);
    tconv_kernel<<<dim3(16, 3),  dim3(256), 0, stream>>>(w_dq_n,  wDqNT,  96,   512);
    tconv_kernel<<<dim3(32, 3),  dim3(256), 0, stream>>>(w_dq_r,  wDqRT,  96,   1024);
    tconv_kernel<<<dim3(4, 32),  dim3(256), 0, stream>>>(w_ckv,   wCkvT,  1024, 32);
    tconv_kernel<<<dim3(16, 1),  dim3(256), 0, stream>>>(w_dk_n,  wDkNT,  32,   512);
    tconv_kernel<<<dim3(48, 1),  dim3(256), 0, stream>>>(w_dv,    wDvT,   32,   1536);
    tconv_kernel<<<dim3(32, 1),  dim3(256), 0, stream>>>(w_k_r,   wKrT,   32,   1024);
    tconv_kernel<<<dim3(48, 32), dim3(256), 0, stream>>>(w_sel_k, wSelKT, 1024, 1536);
    tconv_kernel<<<dim3(48, 32), dim3(256), 0, stream>>>(w_sel_v, wSelVT, 1024, 1536);
    tconv_kernel<<<dim3(48, 32), dim3(256), 0, stream>>>(w_win_k, wWinKT, 1024, 1536);
    tconv_kernel<<<dim3(48, 32), dim3(256), 0, stream>>>(w_win_v, wWinVT, 1024, 1536);
    tconv_kernel<<<dim3(32, 48), dim3(256), 0, stream>>>(w_proj,  wProjT, 1536, 1024);

    // 1) latents + RMS
    gemm_bf16_64<float><<<dim3(1, 32), dim3(256), 0, stream>>>(xb, wCqT,  qlatf,  TT, 96, CC);
    gemm_bf16_64<float><<<dim3(1, 32), dim3(256), 0, stream>>>(xb, wCkvT, kvlatf, TT, 32, CC);
    rms_kernel<<<dim3(TT), dim3(64), 0, stream>>>(qlatf,  qlatb,  q_scale,  96);
    rms_kernel<<<dim3(TT), dim3(64), 0, stream>>>(kvlatf, kvlatb, kv_scale, 32);

    // 2) gate + scores + topk + gather (all deterministic)
    gate_scores_kernel<<<dim3(TT), dim3(256), 0, stream>>>(x, w_gate, w_imp, b_imp, gpart, score);
    gate_finalize_kernel<<<dim3(1), dim3(256), 0, stream>>>(gpart, b_gate, gate);
    topk_kernel<<<dim3(1), dim3(1024), 0, stream>>>(score, idx);
    gather_kernel<<<dim3(SKEEP * 128 / 256), dim3(256), 0, stream>>>(xb, idx, selxb);

    // 3) Q assembly
    gemm_bf16_64<unsigned short><<<dim3(4, 32), dim3(256), 0, stream>>>(qlatb, wDqNT, flatn, TT, 512, 96);
    gemm_bf16_64<unsigned short><<<dim3(8, 32), dim3(256), 0, stream>>>(qlatb, wDqRT, flatr, TT, 1024, 96);
    assemble_split_kernel<<<dim3(TT * HH * 32 / 256), dim3(256), 0, stream>>>(flatn, flatr, cosT, sinT, qfb);

    // 4) branch-1 K (row-major) and V^T (operand-swapped GEMM: (kvlat@wDv)^T )
    gemm_bf16_64<unsigned short><<<dim3(4, 32), dim3(256), 0, stream>>>(kvlatb, wDkNT, flatn, TT, 512, 32);
    gemm_bf16_64<unsigned short><<<dim3(8, 32), dim3(256), 0, stream>>>(kvlatb, wKrT, flatr, TT, 1024, 32);
    assemble_split_kernel<<<dim3(TT * HH * 32 / 256), dim3(256), 0, stream>>>(flatn, flatr, cosT, sinT, k1b);
    gemm_bf16_64<unsigned short><<<dim3(16, 24), dim3(256), 0, stream>>>(wDvT, kvlatb, vt1, 1536, TT, 32);

    // 5) window branch: K row-major + RoPE; V^T direct
    gemm_bf16<unsigned short><<<dim3(12, 16), dim3(256), 0, stream>>>(xb, wWinKT, kwb, TT, 1536, CC);
    rope_inplace_kernel<<<dim3(TT * HH * 32 / 256), dim3(256), 0, stream>>>(kwb, cosT, sinT, TT);
    gemm_bf16<unsigned short><<<dim3(16, 12), dim3(256), 0, stream>>>(wWinVT, xb, vtw, 1536, TT, CC);

    // 6) selected branch: K + RoPE; V^T direct
    gemm_bf16_64<unsigned short><<<dim3(12, 8), dim3(256), 0, stream>>>(selxb, wSelKT, ksb, SKEEP, 1536, CC);
    rope_inplace_kernel<<<dim3(SKEEP * HH * 32 / 256), dim3(256), 0, stream>>>(ksb, cosT, sinT, SKEEP);
    gemm_bf16_64<unsigned short><<<dim3(4, 24), dim3(256), 0, stream>>>(wSelVT, selxb, vts, 1536, SKEEP, CC);

    // 7) fused 3-branch attention -> ob
    fused_attn_kernel<<<dim3(TT / BQ, HH), dim3(512), 0, stream>>>(
        qfb, k1b, vt1, ksb, vts, kwb, vtw, gate, ob);

    // 8) output projection
    gemm_bf16_64<float><<<dim3(8, 32), dim3(256), 0, stream>>>(ob, wProjT, out, TT, CC, 1536);
}

// Round 7
// 436.612 us; speedup vs baseline: 5.6299x; 1.2950x over previous
//
#include <hip/hip_runtime.h>
#include <cmath>

#define TT 2048
#define CC 1024
#define HH 16
#define SKEEP 512

typedef __attribute__((ext_vector_type(8))) short bf16x8;
typedef __attribute__((ext_vector_type(4))) float f32x4;
typedef __attribute__((ext_vector_type(8))) unsigned short u16x8;

__device__ __forceinline__ unsigned short f2bf(float f) {
    union { float f; unsigned int u; } v; v.f = f;
    unsigned int r = v.u + 0x7fffu + ((v.u >> 16) & 1u);
    return (unsigned short)(r >> 16);
}
__device__ __forceinline__ float bf2f(unsigned short b) {
    union { unsigned int u; float f; } v; v.u = ((unsigned int)b) << 16;
    return v.f;
}

#define GLOAD16(gp, lp) __builtin_amdgcn_global_load_lds( \
    (const __attribute__((address_space(1))) void*)(gp),  \
    (__attribute__((address_space(3))) void*)(lp), 16, 0, 0)

// ---------------- workspace byte offsets (~74 MB) ----------------
static constexpr size_t B_COS   = 0;
static constexpr size_t B_SIN   = 262144;
static constexpr size_t B_XB    = 524288;       // 2048*1024 bf16
static constexpr size_t B_WCQT  = 4718592;      // 128x1024 (pad 96->128)
static constexpr size_t B_WDQN  = 4980736;      // 512x96
static constexpr size_t B_WDQR  = 5079040;      // 1024x96
static constexpr size_t B_WCKVT = 5275648;      // 128x1024 (pad 32->128)
static constexpr size_t B_WDKN  = 5537792;      // 512x32
static constexpr size_t B_WDVT  = 5570560;      // 1536x32
static constexpr size_t B_WKRT  = 5668864;      // 1024x32
static constexpr size_t B_WSELK = 5734400;      // 1536x1024
static constexpr size_t B_WSELV = 8880128;
static constexpr size_t B_WWINK = 12025856;
static constexpr size_t B_WWINV = 15171584;
static constexpr size_t B_WPROJ = 18317312;     // 1024x1536
static constexpr size_t B_QLATF = 21463040;     // 2048*96 f32
static constexpr size_t B_KVLATF= 22249472;     // 2048*32 f32
static constexpr size_t B_QLATB = 22511616;     // 2048*96 bf16
static constexpr size_t B_KVLATB= 22904832;     // 2048*32 bf16
static constexpr size_t B_GPART = 23035904;     // 2048*3 f32
static constexpr size_t B_GATE  = 23060480;
static constexpr size_t B_SCORE = 23060736;
static constexpr size_t B_IDX   = 23068928;
static constexpr size_t B_SELXB = 23070976;     // 512*1024 bf16
static constexpr size_t B_FLATNQ= 24119552;     // 2048*512 bf16
static constexpr size_t B_FLATRQ= 26216704;     // 2048*1024 bf16
static constexpr size_t B_FLATNK= 30411008;
static constexpr size_t B_FLATRK= 32508160;
static constexpr size_t B_QFB   = 36702464;     // 2048*1536 bf16
static constexpr size_t B_K1B   = 42993920;
static constexpr size_t B_VT1   = 49285376;     // V1^T [1536][2048]
static constexpr size_t B_KWB   = 55576832;
static constexpr size_t B_VTW   = 61868288;
static constexpr size_t B_KSB   = 68159744;     // [512][1536]
static constexpr size_t B_VTS   = 69732608;     // [1536][512]
static constexpr size_t B_OB    = 71305472;     // [2048][1536] bf16

// ---------------- prep batch: x-convert + rope tables + all weight transposes ----------------
struct TJob { const float* src; unsigned short* dst; int K, N, nx, start; };
struct PrepArgs {
    TJob t[12]; int ntj;
    const float* x; unsigned short* xb;
    float* cosT; float* sinT;
};

__global__ __launch_bounds__(256) void prep_batch(PrepArgs P) {
    const int bid = blockIdx.x, tid = threadIdx.x;
    if (bid < 2048) {                      // convert x -> bf16
        int i = bid * 256 + tid;           // TT*CC/4 float4s
        float4 v = ((const float4*)P.x)[i];
        ushort4 o;
        o.x = f2bf(v.x); o.y = f2bf(v.y); o.z = f2bf(v.z); o.w = f2bf(v.w);
        ((ushort4*)P.xb)[i] = o;
        return;
    }
    if (bid < 2304) {                      // rope tables
        int i = (bid - 2048) * 256 + tid;  // TT*32
        int t = i >> 5, j = i & 31;
        float inv = (float)exp(-(double)j * (9.210340371976184 / 32.0));
        float f = (float)t * inv;
        P.cosT[i] = (float)cos((double)f);
        P.sinT[i] = (float)sin((double)f);
        return;
    }
    // transpose-convert jobs: src f32 [K,N] -> dst bf16 [NP,K], zero-pad rows
    int b = bid - 2304;
    int j = 0;
    while (j + 1 < P.ntj && b >= P.t[j + 1].start) ++j;
    const TJob& J = P.t[j];
    int lb = b - J.start;
    int bx = lb % J.nx, by = lb / J.nx;
    int n0 = bx * 32, k0 = by * 32;
    __shared__ float tile[32][33];
    int tx = tid & 31, ty = tid >> 5;
    #pragma unroll
    for (int r = ty; r < 32; r += 8) {
        float v = 0.f;
        if (n0 + tx < J.N) v = J.src[(size_t)(k0 + r) * J.N + n0 + tx];
        tile[r][tx] = v;
    }
    __syncthreads();
    #pragma unroll
    for (int r = ty; r < 32; r += 8)
        J.dst[(size_t)(n0 + r) * J.K + k0 + tx] = f2bf(tile[tx][r]);
}

// ---------------- batched bf16 MFMA GEMM (64x128 tile): C = A[M,K] * BT[N,K]^T ----------------
struct GJob { const unsigned short* A; const unsigned short* BT; void* C;
              int M, N, K, f32o, start; };
struct GJobs { GJob j[6]; int nj; };

__global__ __launch_bounds__(256) void gemm_batch(GJobs G) {
    const int bid = blockIdx.x, tid = threadIdx.x;
    int ji = 0;
    while (ji + 1 < G.nj && bid >= G.j[ji + 1].start) ++ji;
    const GJob& J = G.j[ji];
    const int lb = bid - J.start;
    const int nbx = (J.N + 127) >> 7;
    const int m0 = (lb / nbx) * 64, n0 = (lb % nbx) * 128;
    const int N = J.N, K = J.K;
    __shared__ unsigned short As[64 * 32];
    __shared__ unsigned short Bs[128 * 32];
    const int lane = tid & 63, lr = lane & 15, lg = lane >> 4;
    const int wave = tid >> 6;
    const int wn = wave * 32;
    f32x4 acc[4][2];
    #pragma unroll
    for (int i = 0; i < 4; ++i)
        #pragma unroll
        for (int j = 0; j < 2; ++j) acc[i][j] = (f32x4){0.f, 0.f, 0.f, 0.f};
    const int ar = tid >> 2, ak = (tid & 3) * 8;
    const unsigned short* ga = J.A + (size_t)(m0 + ar) * K + ak;
    const unsigned short* gb = J.BT + (size_t)(n0 + ar) * K + ak;
    for (int k0 = 0; k0 < K; k0 += 32) {
        GLOAD16(ga + k0, &As[tid * 8]);
        GLOAD16(gb + k0, &Bs[tid * 8]);
        GLOAD16(gb + (size_t)64 * K + k0, &Bs[2048 + tid * 8]);
        __syncthreads();
        bf16x8 af[4], bfr[2];
        #pragma unroll
        for (int i = 0; i < 4; ++i) af[i] = *(const bf16x8*)&As[(i * 16 + lr) * 32 + lg * 8];
        #pragma unroll
        for (int j = 0; j < 2; ++j) bfr[j] = *(const bf16x8*)&Bs[(wn + j * 16 + lr) * 32 + lg * 8];
        #pragma unroll
        for (int i = 0; i < 4; ++i)
            #pragma unroll
            for (int j = 0; j < 2; ++j)
                acc[i][j] = __builtin_amdgcn_mfma_f32_16x16x32_bf16(af[i], bfr[j], acc[i][j], 0, 0, 0);
        __syncthreads();
    }
    #pragma unroll
    for (int i = 0; i < 4; ++i) {
        #pragma unroll
        for (int r = 0; r < 4; ++r) {
            int row = m0 + i * 16 + lg * 4 + r;
            #pragma unroll
            for (int j = 0; j < 2; ++j) {
                int col = n0 + wn + j * 16 + lr;
                if (col < N) {
                    float v = acc[i][j][r];
                    if (J.f32o) ((float*)J.C)[(size_t)row * N + col] = v;
                    else        ((unsigned short*)J.C)[(size_t)row * N + col] = f2bf(v);
                }
            }
        }
    }
}

// ---------------- RMSNorm batch: q rows then kv rows ----------------
__global__ __launch_bounds__(64) void rms_batch(const float* __restrict__ qlatf,
                                                unsigned short* __restrict__ qlatb,
                                                const float* __restrict__ q_scale,
                                                const float* __restrict__ kvlatf,
                                                unsigned short* __restrict__ kvlatb,
                                                const float* __restrict__ kv_scale) {
    int b = blockIdx.x, lane = threadIdx.x;
    const float* in;
    unsigned short* outb;
    const float* scale;
    int D, t;
    if (b < TT) { in = qlatf; outb = qlatb; scale = q_scale; D = 96; t = b; }
    else        { in = kvlatf; outb = kvlatb; scale = kv_scale; D = 32; t = b - TT; }
    const float* row = in + (size_t)t * D;
    float ss = 0.f;
    for (int d = lane; d < D; d += 64) { float v = row[d]; ss += v * v; }
    #pragma unroll
    for (int o = 32; o > 0; o >>= 1) ss += __shfl_xor(ss, o);
    float rs = 1.0f / sqrtf(ss / (float)D + 1e-6f);
    for (int d = lane; d < D; d += 64) outb[(size_t)t * D + d] = f2bf(row[d] * rs * scale[d]);
}

// ---------------- gate partials + importance scores (no atomics) ----------------
__global__ __launch_bounds__(256) void gate_scores_kernel(const float* __restrict__ x,
                                                          const float* __restrict__ w_gate,
                                                          const float* __restrict__ w_imp,
                                                          const float* __restrict__ b_imp,
                                                          float* __restrict__ gpart,
                                                          float* __restrict__ scores) {
    int t = blockIdx.x;
    const float* xr = x + (size_t)t * CC;
    float g0 = 0, g1 = 0, g2 = 0, si = 0;
    for (int c = threadIdx.x; c < CC; c += 256) {
        float xv = xr[c];
        g0 += xv * w_gate[c * 3 + 0];
        g1 += xv * w_gate[c * 3 + 1];
        g2 += xv * w_gate[c * 3 + 2];
        si += xv * w_imp[c];
    }
    #pragma unroll
    for (int o = 32; o > 0; o >>= 1) {
        g0 += __shfl_xor(g0, o); g1 += __shfl_xor(g1, o);
        g2 += __shfl_xor(g2, o); si += __shfl_xor(si, o);
    }
    __shared__ float red[4][4];
    int w_ = threadIdx.x >> 6, lane = threadIdx.x & 63;
    if (lane == 0) { red[w_][0] = g0; red[w_][1] = g1; red[w_][2] = g2; red[w_][3] = si; }
    __syncthreads();
    if (threadIdx.x == 0) {
        gpart[t * 3 + 0] = red[0][0] + red[1][0] + red[2][0] + red[3][0];
        gpart[t * 3 + 1] = red[0][1] + red[1][1] + red[2][1] + red[3][1];
        gpart[t * 3 + 2] = red[0][2] + red[1][2] + red[2][2] + red[3][2];
        scores[t] = red[0][3] + red[1][3] + red[2][3] + red[3][3] + b_imp[0];
    }
}

// ---------------- top-k bitonic + folded gate finalize ----------------
__global__ __launch_bounds__(1024) void topk_kernel(const float* __restrict__ scores,
                                                    int* __restrict__ idx_out,
                                                    const float* __restrict__ gpart,
                                                    const float* __restrict__ b_gate,
                                                    float* __restrict__ gate) {
    __shared__ float v[2048];
    __shared__ int ixs[2048];
    __shared__ float gred[4][3];
    int tid = threadIdx.x;
    v[tid] = scores[tid];               ixs[tid] = tid;
    v[tid + 1024] = scores[tid + 1024]; ixs[tid + 1024] = tid + 1024;
    // gate finalize with first 4 waves (deterministic fixed order)
    float a0 = 0, a1 = 0, a2 = 0;
    if (tid < 256) {
        #pragma unroll
        for (int i = 0; i < 8; ++i) {
            int t = tid * 8 + i;
            a0 += gpart[t * 3 + 0];
            a1 += gpart[t * 3 + 1];
            a2 += gpart[t * 3 + 2];
        }
        #pragma unroll
        for (int o = 32; o > 0; o >>= 1) {
            a0 += __shfl_xor(a0, o); a1 += __shfl_xor(a1, o); a2 += __shfl_xor(a2, o);
        }
        if ((tid & 63) == 0) { gred[tid >> 6][0] = a0; gred[tid >> 6][1] = a1; gred[tid >> 6][2] = a2; }
    }
    __syncthreads();
    if (tid == 0) {
        float g0 = (gred[0][0] + gred[1][0] + gred[2][0] + gred[3][0]) / (float)TT + b_gate[0];
        float g1 = (gred[0][1] + gred[1][1] + gred[2][1] + gred[3][1]) / (float)TT + b_gate[1];
        float g2 = (gred[0][2] + gred[1][2] + gred[2][2] + gred[3][2]) / (float)TT + b_gate[2];
        float mx = fmaxf(g0, fmaxf(g1, g2));
        float e0 = __expf(g0 - mx), e1 = __expf(g1 - mx), e2 = __expf(g2 - mx);
        float s = e0 + e1 + e2;
        gate[0] = e0 / s; gate[1] = e1 / s; gate[2] = e2 / s;
    }
    __syncthreads();
    for (int k = 2; k <= 2048; k <<= 1) {
        for (int j = k >> 1; j > 0; j >>= 1) {
            #pragma unroll
            for (int half = 0; half < 2; ++half) {
                int i = tid + half * 1024;
                int p = i ^ j;
                if (p > i) {
                    float vi = v[i], vp = v[p];
                    int ii = ixs[i], ip = ixs[p];
                    bool p_before = (vp > vi) || (vp == vi && ip < ii);
                    bool asc = ((i & k) == 0);
                    if (asc ? p_before : !p_before) {
                        v[i] = vp; v[p] = vi; ixs[i] = ip; ixs[p] = ii;
                    }
                }
            }
            __syncthreads();
        }
    }
    for (int k = 2; k <= 512; k <<= 1) {
        for (int j = k >> 1; j > 0; j >>= 1) {
            if (tid < 512) {
                int i = tid, p = i ^ j;
                if (p > i) {
                    int a = ixs[i], b = ixs[p];
                    bool asc = ((i & k) == 0);
                    if (asc ? (b < a) : (b > a)) { ixs[i] = b; ixs[p] = a; }
                }
            }
            __syncthreads();
        }
    }
    if (tid < 512) idx_out[tid] = ixs[tid];
}

// ---------------- gather selected rows ----------------
__global__ __launch_bounds__(256) void gather_kernel(const unsigned short* __restrict__ xb,
                                                     const int* __restrict__ idx,
                                                     unsigned short* __restrict__ sel) {
    int i = blockIdx.x * 256 + threadIdx.x;
    if (i >= SKEEP * 128) return;
    int s = i >> 7, q = i & 127;
    ((u16x8*)sel)[(size_t)s * 128 + q] = ((const u16x8*)xb)[(size_t)idx[s] * 128 + q];
}

// ---------------- assemble + rope batch ----------------
__device__ __forceinline__ void assemble_one(const unsigned short* nope, const unsigned short* rope,
                                             const float* cosT, const float* sinT,
                                             unsigned short* out, int i) {
    int j = i & 31, h = (i >> 5) & 15, t = i >> 9;
    float c = cosT[t * 32 + j], s = sinT[t * 32 + j];
    size_t ob = (size_t)t * 1536 + h * 96;
    out[ob + j] = nope[(size_t)t * 512 + h * 32 + j];
    float a = bf2f(rope[(size_t)t * 1024 + h * 64 + j]);
    float b = bf2f(rope[(size_t)t * 1024 + h * 64 + 32 + j]);
    out[ob + 32 + j] = f2bf(a * c - b * s);
    out[ob + 64 + j] = f2bf(a * s + b * c);
}
__device__ __forceinline__ void rope_one(unsigned short* buf, const float* cosT,
                                         const float* sinT, int i) {
    int j = i & 31, h = (i >> 5) & 15, t = i >> 9;
    float c = cosT[t * 32 + j], s = sinT[t * 32 + j];
    unsigned short* p = buf + (size_t)t * 1536 + h * 96;
    float a = bf2f(p[32 + j]), b = bf2f(p[64 + j]);
    p[32 + j] = f2bf(a * c - b * s);
    p[64 + j] = f2bf(a * s + b * c);
}

__global__ __launch_bounds__(256) void assemble_batch(
        const unsigned short* fnq, const unsigned short* frq, unsigned short* qfb,
        const unsigned short* fnk, const unsigned short* frk, unsigned short* k1b,
        unsigned short* kwb, unsigned short* ksb,
        const float* cosT, const float* sinT) {
    int bid = blockIdx.x, tid = threadIdx.x;
    if (bid < 4096)       assemble_one(fnq, frq, cosT, sinT, qfb, bid * 256 + tid);
    else if (bid < 8192)  assemble_one(fnk, frk, cosT, sinT, k1b, (bid - 4096) * 256 + tid);
    else if (bid < 12288) rope_one(kwb, cosT, sinT, (bid - 8192) * 256 + tid);
    else                  rope_one(ksb, cosT, sinT, (bid - 12288) * 256 + tid);
}

// ---------------- fused 3-branch MFMA flash attention (balanced 512-block grid) ----------------
// 512 blocks x 256 threads (4 waves x 16 q-rows = BQ 64). K row-major [T][1536] (XOR-swizzled
// LDS chunks); V transposed [1536][Tv] (XOR-swizzled). Single-buffer stage->barrier->compute.
#define KVB 64
__global__ __launch_bounds__(256) void fused_attn_kernel(
        const unsigned short* __restrict__ qf,
        const unsigned short* __restrict__ k1, const unsigned short* __restrict__ vt1,
        const unsigned short* __restrict__ ksel, const unsigned short* __restrict__ vts,
        const unsigned short* __restrict__ kw, const unsigned short* __restrict__ vtw,
        const float* __restrict__ gate, unsigned short* __restrict__ ob) {
    __shared__ unsigned short Ks[KVB * 96];      // [key][12 chunks], chunk-XOR-swizzled
    __shared__ unsigned short Vs[96 * KVB];      // [d][8 chunks], chunk-XOR-swizzled
    __shared__ unsigned short Ps[4][16 * 72];
    // balanced mapping: CU-slot ci hosts q-tiles (16+k) and (15-k) of the same head
    const int i = blockIdx.x;                    // 0..511
    const int ci = i & 255, half = i >> 8;
    const int xcd = ci >> 5, slot = ci & 31;
    const int h = xcd * 2 + (slot >> 4);
    const int kk_ = slot & 15;
    const int tt = half ? (15 - kk_) : (16 + kk_);
    const int t0 = tt * 64;
    const int tid = threadIdx.x, wave = tid >> 6, lane = tid & 63;
    const int lr = lane & 15, lg = lane >> 4;
    const float SCALE = 0.10206207261596575f;    // 1/sqrt(96)

    bf16x8 qfrag[3];
    {
        const unsigned short* qp = qf + (size_t)(t0 + wave * 16 + lr) * 1536 + h * 96 + lg * 8;
        qfrag[0] = *(const bf16x8*)qp;
        qfrag[1] = *(const bf16x8*)(qp + 32);
        qfrag[2] = *(const bf16x8*)(qp + 64);
    }
    float outv[6][4];
    #pragma unroll
    for (int j = 0; j < 6; ++j)
        #pragma unroll
        for (int r = 0; r < 4; ++r) outv[j][r] = 0.f;

    // stage one 64-key tile: K 768 chunks + V 768 chunks, 3 per thread each
    auto stage = [&](const unsigned short* Kp, const unsigned short* Vtp, int vstr, int k0) {
        #pragma unroll
        for (int rep = 0; rep < 3; ++rep) {
            int c = tid + rep * 256;
            int r = c / 12, q = c % 12;
            int g = (q < 8) ? (q ^ (r & 7)) : (8 + ((q - 8) ^ (r & 3)));
            GLOAD16(Kp + (size_t)(k0 + r) * 1536 + h * 96 + g * 8, &Ks[c * 8]);
            int d = c >> 3, scb = (c & 7) ^ (d & 7);
            GLOAD16(Vtp + (size_t)(h * 96 + d) * vstr + k0 + scb * 8, &Vs[c * 8]);
        }
    };

    for (int b = 0; b < 3; ++b) {
        const unsigned short* Kp  = (b == 0) ? k1  : ((b == 1) ? ksel : kw);
        const unsigned short* Vtp = (b == 0) ? vt1 : ((b == 1) ? vts  : vtw);
        const int vstr = (b == 1) ? SKEEP : TT;
        const bool causal = (b != 1);
        const int nt = causal ? (tt + 1) : (SKEEP / KVB);
        f32x4 oacc[6];
        #pragma unroll
        for (int j = 0; j < 6; ++j) oacc[j] = (f32x4){0.f, 0.f, 0.f, 0.f};
        float m[4], l[4];
        #pragma unroll
        for (int r = 0; r < 4; ++r) { m[r] = -1e30f; l[r] = 0.f; }

        for (int t = 0; t < nt; ++t) {
            const int k0 = t * KVB;
            stage(Kp, Vtp, vstr, k0);
            __syncthreads();                     // vmcnt(0) drain: tile staged
            const bool active = !causal || (k0 <= t0 + wave * 16 + 15);
            if (active) {
                // QK^T
                f32x4 s[4];
                #pragma unroll
                for (int c = 0; c < 4; ++c) s[c] = (f32x4){0.f, 0.f, 0.f, 0.f};
                #pragma unroll
                for (int ds = 0; ds < 3; ++ds) {
                    const int q = (ds < 2) ? ((ds * 4 + lg) ^ (lr & 7)) : (8 + (lg ^ (lr & 3)));
                    #pragma unroll
                    for (int c = 0; c < 4; ++c) {
                        bf16x8 kb = *(const bf16x8*)&Ks[((c * 16 + lr) * 12 + q) * 8];
                        s[c] = __builtin_amdgcn_mfma_f32_16x16x32_bf16(qfrag[ds], kb, s[c], 0, 0, 0);
                    }
                }
                // online softmax
                #pragma unroll
                for (int r = 0; r < 4; ++r) {
                    const int qrow = t0 + wave * 16 + lg * 4 + r;
                    float a0 = s[0][r] * SCALE, a1 = s[1][r] * SCALE;
                    float a2 = s[2][r] * SCALE, a3 = s[3][r] * SCALE;
                    if (causal) {
                        if (k0 + lr > qrow)      a0 = -1e30f;
                        if (k0 + 16 + lr > qrow) a1 = -1e30f;
                        if (k0 + 32 + lr > qrow) a2 = -1e30f;
                        if (k0 + 48 + lr > qrow) a3 = -1e30f;
                    }
                    float mx = fmaxf(fmaxf(a0, a1), fmaxf(a2, a3));
                    mx = fmaxf(mx, __shfl_xor(mx, 1));
                    mx = fmaxf(mx, __shfl_xor(mx, 2));
                    mx = fmaxf(mx, __shfl_xor(mx, 4));
                    mx = fmaxf(mx, __shfl_xor(mx, 8));
                    float mn = fmaxf(m[r], mx);
                    float alpha = __expf(m[r] - mn);
                    m[r] = mn;
                    float p0 = __expf(a0 - mn), p1 = __expf(a1 - mn);
                    float p2 = __expf(a2 - mn), p3 = __expf(a3 - mn);
                    float ps = (p0 + p1) + (p2 + p3);
                    ps += __shfl_xor(ps, 1);
                    ps += __shfl_xor(ps, 2);
                    ps += __shfl_xor(ps, 4);
                    ps += __shfl_xor(ps, 8);
                    l[r] = l[r] * alpha + ps;
                    #pragma unroll
                    for (int j = 0; j < 6; ++j) oacc[j][r] *= alpha;
                    const int pb = (lg * 4 + r) * 72;
                    Ps[wave][pb + lr]      = f2bf(p0);
                    Ps[wave][pb + 16 + lr] = f2bf(p1);
                    Ps[wave][pb + 32 + lr] = f2bf(p2);
                    Ps[wave][pb + 48 + lr] = f2bf(p3);
                }
                // PV
                #pragma unroll
                for (int ks = 0; ks < 2; ++ks) {
                    bf16x8 pf = *(const bf16x8*)&Ps[wave][lr * 72 + ks * 32 + lg * 8];
                    #pragma unroll
                    for (int j = 0; j < 6; ++j) {
                        const int d = j * 16 + lr;
                        const int cb = (ks * 4 + lg) ^ (lr & 7);
                        bf16x8 vb = *(const bf16x8*)&Vs[d * 64 + cb * 8];
                        oacc[j] = __builtin_amdgcn_mfma_f32_16x16x32_bf16(pf, vb, oacc[j], 0, 0, 0);
                    }
                }
            }
            __syncthreads();                     // reads done before next stage overwrites
        }
        const float g = gate[b];
        #pragma unroll
        for (int r = 0; r < 4; ++r) {
            float wgt = g / l[r];
            #pragma unroll
            for (int j = 0; j < 6; ++j) outv[j][r] += oacc[j][r] * wgt;
        }
    }
    #pragma unroll
    for (int r = 0; r < 4; ++r) {
        size_t base = (size_t)(t0 + wave * 16 + lg * 4 + r) * 1536 + h * 96;
        #pragma unroll
        for (int j = 0; j < 6; ++j) ob[base + j * 16 + lr] = f2bf(outv[j][r]);
    }
}

// ---------------- launch ----------------
extern "C" void kernel_launch(void* const* d_in, const int* in_sizes, int n_in,
                              void* d_out, int out_size, void* d_ws, size_t ws_size,
                              hipStream_t stream) {
    const float* x        = (const float*)d_in[0];
    const float* w_cq     = (const float*)d_in[1];
    const float* q_scale  = (const float*)d_in[2];
    const float* w_dq_n   = (const float*)d_in[3];
    const float* w_dq_r   = (const float*)d_in[4];
    const float* w_ckv    = (const float*)d_in[5];
    const float* kv_scale = (const float*)d_in[6];
    const float* w_dk_n   = (const float*)d_in[7];
    const float* w_dv     = (const float*)d_in[8];
    const float* w_k_r    = (const float*)d_in[9];
    const float* w_imp    = (const float*)d_in[10];
    const float* b_imp    = (const float*)d_in[11];
    const float* w_sel_k  = (const float*)d_in[12];
    const float* w_sel_v  = (const float*)d_in[13];
    const float* w_win_k  = (const float*)d_in[14];
    const float* w_win_v  = (const float*)d_in[15];
    const float* w_gate   = (const float*)d_in[16];
    const float* b_gate   = (const float*)d_in[17];
    const float* w_proj   = (const float*)d_in[18];
    float* out = (float*)d_out;
    char* ws = (char*)d_ws;

    float* cosT   = (float*)(ws + B_COS);
    float* sinT   = (float*)(ws + B_SIN);
    unsigned short* xb     = (unsigned short*)(ws + B_XB);
    unsigned short* wCqT   = (unsigned short*)(ws + B_WCQT);
    unsigned short* wDqNT  = (unsigned short*)(ws + B_WDQN);
    unsigned short* wDqRT  = (unsigned short*)(ws + B_WDQR);
    unsigned short* wCkvT  = (unsigned short*)(ws + B_WCKVT);
    unsigned short* wDkNT  = (unsigned short*)(ws + B_WDKN);
    unsigned short* wDvT   = (unsigned short*)(ws + B_WDVT);
    unsigned short* wKrT   = (unsigned short*)(ws + B_WKRT);
    unsigned short* wSelKT = (unsigned short*)(ws + B_WSELK);
    unsigned short* wSelVT = (unsigned short*)(ws + B_WSELV);
    unsigned short* wWinKT = (unsigned short*)(ws + B_WWINK);
    unsigned short* wWinVT = (unsigned short*)(ws + B_WWINV);
    unsigned short* wProjT = (unsigned short*)(ws + B_WPROJ);
    float* qlatf  = (float*)(ws + B_QLATF);
    float* kvlatf = (float*)(ws + B_KVLATF);
    unsigned short* qlatb  = (unsigned short*)(ws + B_QLATB);
    unsigned short* kvlatb = (unsigned short*)(ws + B_KVLATB);
    float* gpart  = (float*)(ws + B_GPART);
    float* gate   = (float*)(ws + B_GATE);
    float* score  = (float*)(ws + B_SCORE);
    int*   idx    = (int*)(ws + B_IDX);
    unsigned short* selxb  = (unsigned short*)(ws + B_SELXB);
    unsigned short* fnq    = (unsigned short*)(ws + B_FLATNQ);
    unsigned short* frq    = (unsigned short*)(ws + B_FLATRQ);
    unsigned short* fnk    = (unsigned short*)(ws + B_FLATNK);
    unsigned short* frk    = (unsigned short*)(ws + B_FLATRK);
    unsigned short* qfb    = (unsigned short*)(ws + B_QFB);
    unsigned short* k1b    = (unsigned short*)(ws + B_K1B);
    unsigned short* vt1    = (unsigned short*)(ws + B_VT1);
    unsigned short* kwb    = (unsigned short*)(ws + B_KWB);
    unsigned short* vtw    = (unsigned short*)(ws + B_VTW);
    unsigned short* ksb    = (unsigned short*)(ws + B_KSB);
    unsigned short* vts    = (unsigned short*)(ws + B_VTS);
    unsigned short* ob     = (unsigned short*)(ws + B_OB);

    // 1) prep batch: convert + rope tables + 12 transposes (10480 blocks)
    PrepArgs P;
    P.x = x; P.xb = xb; P.cosT = cosT; P.sinT = sinT;
    int st = 0, ji = 0;
    auto addT = [&](const float* s, unsigned short* d, int K, int N) {
        int nx = (N + 31) / 32;
        if (s == w_cq || s == w_ckv) nx = 4;           // pad rows to 128
        P.t[ji] = {s, d, K, N, nx, st};
        st += nx * (K / 32); ++ji;
    };
    addT(w_sel_k, wSelKT, 1024, 1536);
    addT(w_sel_v, wSelVT, 1024, 1536);
    addT(w_win_k, wWinKT, 1024, 1536);
    addT(w_win_v, wWinVT, 1024, 1536);
    addT(w_proj,  wProjT, 1536, 1024);
    addT(w_cq,    wCqT,   1024, 96);
    addT(w_ckv,   wCkvT,  1024, 32);
    addT(w_dq_n,  wDqNT,  96,   512);
    addT(w_dq_r,  wDqRT,  96,   1024);
    addT(w_dk_n,  wDkNT,  32,   512);
    addT(w_dv,    wDvT,   32,   1536);
    addT(w_k_r,   wKrT,   32,   1024);
    P.ntj = ji;
    prep_batch<<<dim3(2304 + st), dim3(256), 0, stream>>>(P);

    // 2) gate partials + scores; 3) topk (+gate finalize); 4) gather
    gate_scores_kernel<<<dim3(TT), dim3(256), 0, stream>>>(x, w_gate, w_imp, b_imp, gpart, score);
    topk_kernel<<<dim3(1), dim3(1024), 0, stream>>>(score, idx, gpart, b_gate, gate);
    gather_kernel<<<dim3(SKEEP * 128 / 256), dim3(256), 0, stream>>>(xb, idx, selxb);

    // 5) GEMM batch A: winK, winV^T, selK, selV^T, latents (1024 blocks)
    {
        GJobs G; int s = 0, n = 0;
        auto add = [&](const unsigned short* A, const unsigned short* BT, void* C,
                       int M, int N, int K, int f32o) {
            G.j[n] = {A, BT, C, M, N, K, f32o, s};
            s += ((N + 127) >> 7) * (M / 64); ++n;
        };
        add(xb,     wWinKT, kwb,    2048, 1536, 1024, 0);
        add(wWinVT, xb,     vtw,    1536, 2048, 1024, 0);
        add(selxb,  wSelKT, ksb,    512,  1536, 1024, 0);
        add(wSelVT, selxb,  vts,    1536, 512,  1024, 0);
        add(xb,     wCqT,   qlatf,  2048, 96,   1024, 1);
        add(xb,     wCkvT,  kvlatf, 2048, 32,   1024, 1);
        G.nj = n;
        gemm_batch<<<dim3(s), dim3(256), 0, stream>>>(G);
    }

    // 6) RMS batch
    rms_batch<<<dim3(2 * TT), dim3(64), 0, stream>>>(qlatf, qlatb, q_scale, kvlatf, kvlatb, kv_scale);

    // 7) GEMM batch B: dq/dk decompress + V1^T (1152 blocks)
    {
        GJobs G; int s = 0, n = 0;
        auto add = [&](const unsigned short* A, const unsigned short* BT, void* C,
                       int M, int N, int K, int f32o) {
            G.j[n] = {A, BT, C, M, N, K, f32o, s};
            s += ((N + 127) >> 7) * (M / 64); ++n;
        };
        add(wDvT,   kvlatb, vt1, 1536, 2048, 32, 0);
        add(qlatb,  wDqRT,  frq, 2048, 1024, 96, 0);
        add(kvlatb, wKrT,   frk, 2048, 1024, 32, 0);
        add(qlatb,  wDqNT,  fnq, 2048, 512,  96, 0);
        add(kvlatb, wDkNT,  fnk, 2048, 512,  32, 0);
        G.nj = n;
        gemm_batch<<<dim3(s), dim3(256), 0, stream>>>(G);
    }

    // 8) assemble Q, K1 + rope Kwin, Ksel (13312 blocks)
    assemble_batch<<<dim3(13312), dim3(256), 0, stream>>>(
        fnq, frq, qfb, fnk, frk, k1b, kwb, ksb, cosT, sinT);

    // 9) fused attention (512 balanced blocks)
    fused_attn_kernel<<<dim3(512), dim3(256), 0, stream>>>(
        qfb, k1b, vt1, ksb, vts, kwb, vtw, gate, ob);

    // 10) output projection
    {
        GJobs G;
        G.j[0] = {ob, wProjT, out, 2048, 1024, 1536, 1, 0};
        G.nj = 1;
        gemm_batch<<<dim3(256), dim3(256), 0, stream>>>(G);
    }
}